// Round 1
// baseline (856.107 us; speedup 1.0000x reference)
//
#include <hip/hip_runtime.h>
#include <hip/hip_bf16.h>
#include <math.h>

constexpr int kB    = 64;
constexpr int kN    = 36;
constexpr int kBN   = kB * kN;   // 2304
constexpr int kD    = 2048;
constexpr int kDatt = 512;
constexpr int kPairs = kN * kN;  // 1296
constexpr int kRows  = kB * kPairs; // 82944 total pair-rows

using bf16x8 = __attribute__((ext_vector_type(8))) short;
using f32x4  = __attribute__((ext_vector_type(4))) float;

typedef unsigned int u32;
typedef __attribute__((address_space(3))) u32 lds_u32;
typedef const __attribute__((address_space(1))) u32 glb_u32;

__device__ inline unsigned short f2bf(float f) {
    union { float f; unsigned u; } v; v.f = f;
    unsigned r = v.u + 0x7FFFu + ((v.u >> 16) & 1u);   // RNE
    return (unsigned short)(r >> 16);
}

// ---------------------------------------------------------------------------
// kcvt: f32 -> bf16 elementwise
// ---------------------------------------------------------------------------
__global__ __launch_bounds__(256)
void kcvt(const float* __restrict__ x, unsigned short* __restrict__ y, int n4)
{
    int i = blockIdx.x * 256 + threadIdx.x;
    if (i < n4) {
        float4 v = ((const float4*)x)[i];
        ushort4 o = {f2bf(v.x), f2bf(v.y), f2bf(v.z), f2bf(v.w)};
        ((ushort4*)y)[i] = o;
    }
}

// ---------------------------------------------------------------------------
// ktrp: W[kD][nt] f32 -> WT[nt][kD] bf16 (transpose + convert)
// ---------------------------------------------------------------------------
__global__ __launch_bounds__(256)
void ktrp(const float* __restrict__ W, unsigned short* __restrict__ WT, int nt)
{
    __shared__ float T[64][65];
    const int k0 = blockIdx.x * 64;
    const int n0 = blockIdx.y * 64;
    const int c = threadIdx.x & 63, r0 = threadIdx.x >> 6;
    #pragma unroll
    for (int rr = 0; rr < 64; rr += 4)
        T[r0 + rr][c] = W[(size_t)(k0 + r0 + rr) * nt + n0 + c];
    __syncthreads();
    #pragma unroll
    for (int rr = 0; rr < 64; rr += 4)
        WT[(size_t)(n0 + r0 + rr) * kD + k0 + c] = f2bf(T[c][r0 + rr]);
}

// ---------------------------------------------------------------------------
// K3: ba/bb = box @ Wba/Wbb, K=4 -> elementwise
// ---------------------------------------------------------------------------
__global__ __launch_bounds__(256)
void k3_box_proj(const float* __restrict__ box, const float* __restrict__ Wba,
                 const float* __restrict__ Wbb,
                 float* __restrict__ ba, float* __restrict__ bb)
{
    const int r = blockIdx.y;
    const int c = blockIdx.x * 256 + threadIdx.x;
    const float x0 = box[r * 4 + 0], x1 = box[r * 4 + 1];
    const float x2 = box[r * 4 + 2], x3 = box[r * 4 + 3];
    float va = x0 * Wba[c] + x1 * Wba[kD + c] + x2 * Wba[2 * kD + c] + x3 * Wba[3 * kD + c];
    float vb = x0 * Wbb[c] + x1 * Wbb[kD + c] + x2 * Wbb[2 * kD + c] + x3 * Wbb[3 * kD + c];
    ba[(size_t)r * kD + c] = va;
    bb[(size_t)r * kD + c] = vb;
}

// ---------------------------------------------------------------------------
// Staging helpers for k1/k2: Rx32 bf16 tiles via global_load_lds width=16.
// ---------------------------------------------------------------------------
__device__ inline void stage128(const unsigned short* __restrict__ g,
                                int grow0, int k0,
                                unsigned short* lds, int w, int lane)
{
    const int sr = lane >> 2, sc = (lane & 3) * 8;
    #pragma unroll
    for (int t = 0; t < 2; ++t) {
        int r = w * 32 + t * 16;
        const unsigned short* gp = g + (size_t)(grow0 + r + sr) * kD + k0 + sc;
        __builtin_amdgcn_global_load_lds((glb_u32*)gp, (lds_u32*)(lds + r * 32), 16, 0, 0);
    }
}
__device__ inline void stage64(const unsigned short* __restrict__ g,
                               int grow0, int k0,
                               unsigned short* lds, int w, int lane)
{
    const int sr = lane >> 2, sc = (lane & 3) * 8;
    int r = w * 16;
    const unsigned short* gp = g + (size_t)(grow0 + r + sr) * kD + k0 + sc;
    __builtin_amdgcn_global_load_lds((glb_u32*)gp, (lds_u32*)(lds + r * 32), 16, 0, 0);
}

// ---------------------------------------------------------------------------
// K1 (MFMA dual): fused_bf16 = bf16((Qb @ WqT') .* (Ob @ WoT')), 128x64 tile
// ---------------------------------------------------------------------------
__global__ __launch_bounds__(256, 2)
void k1_dual_mfma(const unsigned short* __restrict__ Qb,
                  const unsigned short* __restrict__ WqT,
                  const unsigned short* __restrict__ Ob,
                  const unsigned short* __restrict__ WoT,
                  unsigned short* __restrict__ fusedb)
{
    __shared__ __align__(16) unsigned short As1[128][32];
    __shared__ __align__(16) unsigned short As2[128][32];
    __shared__ __align__(16) unsigned short Bs1[64][32];
    __shared__ __align__(16) unsigned short Bs2[64][32];

    const int tid = threadIdx.x;
    const int lane = tid & 63;
    const int w = tid >> 6;
    const int wm = w >> 1, wn = w & 1;
    const int row0 = blockIdx.y * 128;
    const int col0 = blockIdx.x * 64;

    f32x4 acc1[4][2], acc2[4][2];
    #pragma unroll
    for (int mt = 0; mt < 4; ++mt)
        #pragma unroll
        for (int nt = 0; nt < 2; ++nt) { acc1[mt][nt] = (f32x4)(0.f); acc2[mt][nt] = (f32x4)(0.f); }

    const int fr = lane & 15, ko = (lane >> 4) * 8;

    for (int k0 = 0; k0 < kD; k0 += 32) {
        stage128(Qb,  row0, k0, &As1[0][0], w, lane);
        stage128(Ob,  row0, k0, &As2[0][0], w, lane);
        stage64 (WqT, col0, k0, &Bs1[0][0], w, lane);
        stage64 (WoT, col0, k0, &Bs2[0][0], w, lane);
        __syncthreads();

        bf16x8 a1[4], a2[4];
        #pragma unroll
        for (int mt = 0; mt < 4; ++mt) {
            a1[mt] = *(bf16x8*)&As1[wm * 64 + mt * 16 + fr][ko];
            a2[mt] = *(bf16x8*)&As2[wm * 64 + mt * 16 + fr][ko];
        }
        #pragma unroll
        for (int nt = 0; nt < 2; ++nt) {
            bf16x8 b1 = *(bf16x8*)&Bs1[wn * 32 + nt * 16 + fr][ko];
            bf16x8 b2 = *(bf16x8*)&Bs2[wn * 32 + nt * 16 + fr][ko];
            #pragma unroll
            for (int mt = 0; mt < 4; ++mt) {
                acc1[mt][nt] = __builtin_amdgcn_mfma_f32_16x16x32_bf16(a1[mt], b1, acc1[mt][nt], 0, 0, 0);
                acc2[mt][nt] = __builtin_amdgcn_mfma_f32_16x16x32_bf16(a2[mt], b2, acc2[mt][nt], 0, 0, 0);
            }
        }
        __syncthreads();
    }

    const int fq = lane >> 4;
    #pragma unroll
    for (int mt = 0; mt < 4; ++mt)
        #pragma unroll
        for (int nt = 0; nt < 2; ++nt) {
            int row = row0 + wm * 64 + mt * 16 + fq * 4;
            int col = col0 + wn * 32 + nt * 16 + fr;
            #pragma unroll
            for (int reg = 0; reg < 4; ++reg) {
                float v = acc1[mt][nt][reg] * acc2[mt][nt][reg];
                fusedb[(size_t)(row + reg) * kD + col] = f2bf(v);
            }
        }
}

// ---------------------------------------------------------------------------
// K2 (MFMA dual-B): ra = Fb @ WfaT', rb = Fb @ WfbT', 128x64 tile
// ---------------------------------------------------------------------------
__global__ __launch_bounds__(256, 2)
void k2_dual_mfma(const unsigned short* __restrict__ Fb,
                  const unsigned short* __restrict__ WfaT,
                  const unsigned short* __restrict__ WfbT,
                  float* __restrict__ ra, float* __restrict__ rb)
{
    __shared__ __align__(16) unsigned short As [128][32];
    __shared__ __align__(16) unsigned short Bs1[64][32];
    __shared__ __align__(16) unsigned short Bs2[64][32];

    const int tid = threadIdx.x;
    const int lane = tid & 63;
    const int w = tid >> 6;
    const int wm = w >> 1, wn = w & 1;
    const int row0 = blockIdx.y * 128;
    const int col0 = blockIdx.x * 64;

    f32x4 acc1[4][2], acc2[4][2];
    #pragma unroll
    for (int mt = 0; mt < 4; ++mt)
        #pragma unroll
        for (int nt = 0; nt < 2; ++nt) { acc1[mt][nt] = (f32x4)(0.f); acc2[mt][nt] = (f32x4)(0.f); }

    const int fr = lane & 15, ko = (lane >> 4) * 8;

    for (int k0 = 0; k0 < kD; k0 += 32) {
        stage128(Fb,   row0, k0, &As [0][0], w, lane);
        stage64 (WfaT, col0, k0, &Bs1[0][0], w, lane);
        stage64 (WfbT, col0, k0, &Bs2[0][0], w, lane);
        __syncthreads();

        bf16x8 a[4];
        #pragma unroll
        for (int mt = 0; mt < 4; ++mt)
            a[mt] = *(bf16x8*)&As[wm * 64 + mt * 16 + fr][ko];
        #pragma unroll
        for (int nt = 0; nt < 2; ++nt) {
            bf16x8 b1 = *(bf16x8*)&Bs1[wn * 32 + nt * 16 + fr][ko];
            bf16x8 b2 = *(bf16x8*)&Bs2[wn * 32 + nt * 16 + fr][ko];
            #pragma unroll
            for (int mt = 0; mt < 4; ++mt) {
                acc1[mt][nt] = __builtin_amdgcn_mfma_f32_16x16x32_bf16(a[mt], b1, acc1[mt][nt], 0, 0, 0);
                acc2[mt][nt] = __builtin_amdgcn_mfma_f32_16x16x32_bf16(a[mt], b2, acc2[mt][nt], 0, 0, 0);
            }
        }
        __syncthreads();
    }

    const int fq = lane >> 4;
    #pragma unroll
    for (int mt = 0; mt < 4; ++mt)
        #pragma unroll
        for (int nt = 0; nt < 2; ++nt) {
            int row = row0 + wm * 64 + mt * 16 + fq * 4;
            int col = col0 + wn * 32 + nt * 16 + fr;
            #pragma unroll
            for (int reg = 0; reg < 4; ++reg) {
                size_t o = (size_t)(row + reg) * kD + col;
                ra[o] = acc1[mt][nt][reg];
                rb[o] = acc2[mt][nt][reg];
            }
        }
}

// ---------------------------------------------------------------------------
// K4 v4: single-barrier software pipeline, bank-conflict-free Bs.
//
// Bs staging uses global_load_lds (linear dest, 1024 B per issue = 16 rows
// x 64 B). Rows are 64 B apart -> a naive [512][32] layout gives an 8-way
// bank conflict on the bf fragment reads (16 lanes, stride 64 B, bank start
// period 2). Fix (both-sides permutation, 16-B granule): within each
// 1024-B DMA block, granule l holds (row (l&7)+8*(l>>5), k-granule (l>>3)&3).
// Stage pre-permutes the per-lane GLOBAL source; the read applies the same
// bijection: short off = (R>>4)*512 + ((R>>3)&1)*256 + fq*64 + (R&7)*8.
// 16 consecutive rows then hit byte starts 16*(fr&7)+512*(fr>>3): all 32
// banks exactly 2-way (the b128 floor). Fragments stay contiguous 16 B.
//
// Grid flattened over all 82944 pair-rows -> 648 blocks x 128 rows, all
// valid (no clamp, no tail). LOAD_A issued before ISSUE_B so the wait
// guarding WRITE_REL is a counted vmcnt (DMA stays in flight).
// ---------------------------------------------------------------------------
__global__ __launch_bounds__(512, 2)
void k4_scores_mfma(const float* __restrict__ ra, const float* __restrict__ rb,
                    const float* __restrict__ ba, const float* __restrict__ bb,
                    const unsigned short* __restrict__ W0T,
                    const float* __restrict__ b0, const float* __restrict__ W1,
                    float* __restrict__ scores)
{
    __shared__ __align__(16) unsigned short Bs[2][512 * 32];  // 64 KB
    __shared__ __align__(16) unsigned short RelS[2][128][40]; // 20 KB
    __shared__ float scoreS[128];

    const int tid  = threadIdx.x;
    const int lane = tid & 63;
    const int w    = tid >> 6;        // 0..7
    const int wm   = w >> 2;          // 0..1 : M-half
    const int wn   = w & 3;           // 0..3 : N-quarter (128 cols)
    const int t0   = blockIdx.x * 128;  // global pair-row tile (all rows valid)

    // A-gen slots: 1024 = 128 rows x 8 col-groups; thread does slots tid, tid+512
    int rowA[2], cgA[2];
    const float *raP[2], *rbP[2], *baP[2], *bbP[2];
    #pragma unroll
    for (int t = 0; t < 2; ++t) {
        int s = tid + t * 512;
        rowA[t] = s >> 3; cgA[t] = s & 7;
        int gp = t0 + rowA[t];
        int b  = gp / kPairs;
        int r  = gp - b * kPairs;
        int i  = r / kN, j = r - i * kN;
        raP[t] = ra + (size_t)(b * kN + i) * kD;
        baP[t] = ba + (size_t)(b * kN + i) * kD;
        rbP[t] = rb + (size_t)(b * kN + j) * kD;
        bbP[t] = bb + (size_t)(b * kN + j) * kD;
    }

    const int fr = lane & 15, fq = lane >> 4;
    // Bs staging lane mapping (granule permutation, see header comment)
    const int bsr = (lane & 7) + ((lane >> 5) << 3);
    const int bsc = ((lane >> 3) & 3) * 8;
    // Bs read: per-lane constant part of the permuted short-offset
    const int bco = ((fr & 7) << 3) + ((fr >> 3) << 8) + (fq << 6);

    f32x4 acc[4][8];
    #pragma unroll
    for (int mt = 0; mt < 4; ++mt)
        #pragma unroll
        for (int nt = 0; nt < 8; ++nt)
            acc[mt][nt] = (f32x4)(0.f);

    if (tid < 128) scoreS[tid] = 0.f;

    float4 pa[2], pr[2], pp[2], pq[2];   // prefetched A-gen operands

    #define ISSUE_B(k0_, buf_)                                                   \
        _Pragma("unroll")                                                        \
        for (int t = 0; t < 4; ++t) {                                            \
            int r0 = w * 64 + t * 16;                                            \
            const unsigned short* gp = W0T + (size_t)(r0 + bsr) * kD + (k0_) + bsc;\
            __builtin_amdgcn_global_load_lds((glb_u32*)gp,                       \
                (lds_u32*)&Bs[buf_][r0 * 32], 16, 0, 0);                         \
        }

    #define LOAD_A(k0_)                                                          \
        _Pragma("unroll")                                                        \
        for (int t = 0; t < 2; ++t) {                                            \
            pa[t] = *(const float4*)(raP[t] + (k0_) + cgA[t] * 4);               \
            pr[t] = *(const float4*)(rbP[t] + (k0_) + cgA[t] * 4);               \
            pp[t] = *(const float4*)(baP[t] + (k0_) + cgA[t] * 4);               \
            pq[t] = *(const float4*)(bbP[t] + (k0_) + cgA[t] * 4);               \
        }

    #define WRITE_REL(buf_)                                                      \
        _Pragma("unroll")                                                        \
        for (int t = 0; t < 2; ++t) {                                            \
            ushort4 o;                                                           \
            o.x = f2bf(pa[t].x * pr[t].x + pp[t].x * pq[t].x);                   \
            o.y = f2bf(pa[t].y * pr[t].y + pp[t].y * pq[t].y);                   \
            o.z = f2bf(pa[t].z * pr[t].z + pp[t].z * pq[t].z);                   \
            o.w = f2bf(pa[t].w * pr[t].w + pp[t].w * pq[t].w);                   \
            *(ushort4*)&RelS[buf_][rowA[t]][cgA[t] * 4] = o;                     \
        }

    // prologue: fill buffer 0
    LOAD_A(0)
    ISSUE_B(0, 0)
    WRITE_REL(0)

    for (int k0 = 0; k0 < kD; k0 += 32) {
        const int cur = (k0 >> 5) & 1, nxt = cur ^ 1;
        const bool more = (k0 + 32 < kD);
        __syncthreads();   // Bs[cur] DMA drained; RelS[cur] visible
        if (more) {
            LOAD_A(k0 + 32)         // A-regs in flight during MFMA
            ISSUE_B(k0 + 32, nxt)   // DMA runs during this step's MFMA
        }
        bf16x8 af[4];
        #pragma unroll
        for (int mt = 0; mt < 4; ++mt)
            af[mt] = *(bf16x8*)&RelS[cur][wm * 64 + mt * 16 + fr][fq * 8];
        #pragma unroll
        for (int nt = 0; nt < 8; ++nt) {
            bf16x8 bfv = *(bf16x8*)&Bs[cur][wn * 4096 + nt * 512 + bco];
            #pragma unroll
            for (int mt = 0; mt < 4; ++mt)
                acc[mt][nt] = __builtin_amdgcn_mfma_f32_16x16x32_bf16(af[mt], bfv, acc[mt][nt], 0, 0, 0);
        }
        if (more) { WRITE_REL(nxt) }
    }

    // epilogue: score_row = sum_cols W1*tanh(H + b0); b1 softmax-invariant
    float b0v[8], w1v[8];
    #pragma unroll
    for (int nt = 0; nt < 8; ++nt) {
        int col = wn * 128 + nt * 16 + fr;
        b0v[nt] = b0[col];
        w1v[nt] = W1[col];
    }
    #pragma unroll
    for (int mt = 0; mt < 4; ++mt) {
        #pragma unroll
        for (int reg = 0; reg < 4; ++reg) {
            float p = 0.f;
            #pragma unroll
            for (int nt = 0; nt < 8; ++nt)
                p += w1v[nt] * tanhf(acc[mt][nt][reg] + b0v[nt]);
            p += __shfl_xor(p, 1, 64);
            p += __shfl_xor(p, 2, 64);
            p += __shfl_xor(p, 4, 64);
            p += __shfl_xor(p, 8, 64);
            if (fr == 0)
                atomicAdd(&scoreS[wm * 64 + mt * 16 + fq * 4 + reg], p);
        }
    }
    __syncthreads();
    if (tid < 128)
        scores[(size_t)t0 + tid] = scoreS[tid];
}

// ---------------------------------------------------------------------------
// K5: softmax over j
// ---------------------------------------------------------------------------
__global__ __launch_bounds__(64)
void k5_softmax(const float* __restrict__ scores, float* __restrict__ att)
{
    const int bi = blockIdx.x;
    const int tid = threadIdx.x;
    float s = (tid < kN) ? scores[(size_t)bi * kN + tid] : -1e30f;
    float m = s;
    #pragma unroll
    for (int off = 32; off >= 1; off >>= 1)
        m = fmaxf(m, __shfl_xor(m, off, 64));
    float e = (tid < kN) ? expf(s - m) : 0.f;
    float sum = e;
    #pragma unroll
    for (int off = 32; off >= 1; off >>= 1)
        sum += __shfl_xor(sum, off, 64);
    if (tid < kN) att[(size_t)bi * kN + tid] = e / sum;
}

// ---------------------------------------------------------------------------
// K6: out[b,i,:] = obj + fused + ra_i.(att_i @ RB_b) + ba_i.(att_i @ BB_b)
// ---------------------------------------------------------------------------
__global__ __launch_bounds__(256)
void k6_output(const float* __restrict__ obj, const unsigned short* __restrict__ fusedb,
               const float* __restrict__ ra, const float* __restrict__ ba,
               const float* __restrict__ rb, const float* __restrict__ bb,
               const float* __restrict__ att, float* __restrict__ out)
{
    __shared__ float attS[kN];
    const int bi = blockIdx.x;
    const int b = bi / kN;
    const int tid = threadIdx.x;
    if (tid < kN) attS[tid] = att[(size_t)bi * kN + tid];
    __syncthreads();
    for (int d = tid; d < kD; d += 256) {
        float s1 = 0.f, s2 = 0.f;
        #pragma unroll 4
        for (int j = 0; j < kN; ++j) {
            float a = attS[j];
            size_t rrow = (size_t)(b * kN + j) * kD + d;
            s1 = fmaf(a, rb[rrow], s1);
            s2 = fmaf(a, bb[rrow], s2);
        }
        size_t o = (size_t)bi * kD + d;
        float fv = __uint_as_float((u32)fusedb[o] << 16);
        out[o] = obj[o] + fv + ra[o] * s1 + ba[o] * s2;
    }
}

// ---------------------------------------------------------------------------
extern "C" void kernel_launch(void* const* d_in, const int* in_sizes, int n_in,
                              void* d_out, int out_size, void* d_ws, size_t ws_size,
                              hipStream_t stream)
{
    const float* q   = (const float*)d_in[0];
    const float* obj = (const float*)d_in[1];
    const float* box = (const float*)d_in[2];
    const float* Wq  = (const float*)d_in[3];
    const float* Wo  = (const float*)d_in[4];
    const float* Wfa = (const float*)d_in[5];
    const float* Wfb = (const float*)d_in[6];
    const float* Wba = (const float*)d_in[7];
    const float* Wbb = (const float*)d_in[8];
    const float* W0  = (const float*)d_in[9];
    const float* b0v = (const float*)d_in[10];
    const float* W1  = (const float*)d_in[11];
    // d_in[12] = b1 (softmax-invariant), d_in[13..14] scalars: unused
    float* out = (float*)d_out;

    const size_t nBD = (size_t)kBN * kD;
    float* ws = (float*)d_ws;
    size_t off = 0;
    float* ra     = ws + off; off += nBD;
    float* rb     = ws + off; off += nBD;
    float* ba     = ws + off; off += nBD;
    float* bb     = ws + off; off += nBD;
    float* scores = ws + off; off += (size_t)kBN * kN;
    float* att    = ws + off; off += (size_t)kBN * kN;

    unsigned short* us = (unsigned short*)(ws + off);
    size_t uoff = 0;
    unsigned short* W0T     = us + uoff; uoff += (size_t)kDatt * kD;
    unsigned short* q_bf    = us + uoff; uoff += nBD;
    unsigned short* obj_bf  = us + uoff; uoff += nBD;
    unsigned short* fusedbf = us + uoff; uoff += nBD;
    unsigned short* WqT     = us + uoff; uoff += (size_t)kD * kD;
    unsigned short* WoT     = us + uoff; uoff += (size_t)kD * kD;
    // WfaT/WfbT alias q_bf/obj_bf (dead after k1; stream order guarantees safety)
    unsigned short* WfaT = q_bf;
    unsigned short* WfbT = obj_bf;

    const int n4 = (int)(nBD / 4);
    kcvt<<<dim3((n4 + 255) / 256), 256, 0, stream>>>(q,   q_bf,   n4);
    kcvt<<<dim3((n4 + 255) / 256), 256, 0, stream>>>(obj, obj_bf, n4);
    ktrp<<<dim3(32, 32), 256, 0, stream>>>(Wq, WqT, kD);
    ktrp<<<dim3(32, 32), 256, 0, stream>>>(Wo, WoT, kD);
    ktrp<<<dim3(32, 8),  256, 0, stream>>>(W0, W0T, kDatt);
    k3_box_proj<<<dim3(kD / 256, kBN), 256, 0, stream>>>(box, Wba, Wbb, ba, bb);

    k1_dual_mfma<<<dim3(kD / 64, kBN / 128), 256, 0, stream>>>(q_bf, WqT, obj_bf, WoT, fusedbf);

    ktrp<<<dim3(32, 32), 256, 0, stream>>>(Wfa, WfaT, kD);
    ktrp<<<dim3(32, 32), 256, 0, stream>>>(Wfb, WfbT, kD);

    k2_dual_mfma<<<dim3(kD / 64, kBN / 128), 256, 0, stream>>>(fusedbf, WfaT, WfbT, ra, rb);

    k4_scores_mfma<<<dim3(kRows / 128), 512, 0, stream>>>(ra, rb, ba, bb, W0T, b0v, W1, scores);
    k5_softmax<<<kBN, 64, 0, stream>>>(scores, att);
    k6_output<<<kBN, 256, 0, stream>>>(obj, fusedbf, ra, ba, rb, bb, att, out);
}

// Round 2
// 745.518 us; speedup vs baseline: 1.1483x; 1.1483x over previous
//
#include <hip/hip_runtime.h>
#include <hip/hip_bf16.h>
#include <math.h>

constexpr int kB    = 64;
constexpr int kN    = 36;
constexpr int kBN   = kB * kN;   // 2304
constexpr int kD    = 2048;
constexpr int kDatt = 512;
constexpr int kPairs = kN * kN;  // 1296
constexpr int kRows  = kB * kPairs; // 82944 total pair-rows

using bf16x8 = __attribute__((ext_vector_type(8))) short;
using f32x4  = __attribute__((ext_vector_type(4))) float;

typedef unsigned int u32;
typedef __attribute__((address_space(3))) u32 lds_u32;
typedef const __attribute__((address_space(1))) u32 glb_u32;

__device__ inline unsigned short f2bf(float f) {
    union { float f; unsigned u; } v; v.f = f;
    unsigned r = v.u + 0x7FFFu + ((v.u >> 16) & 1u);   // RNE
    return (unsigned short)(r >> 16);
}

// ---------------------------------------------------------------------------
// kcvt: f32 -> bf16 elementwise
// ---------------------------------------------------------------------------
__global__ __launch_bounds__(256)
void kcvt(const float* __restrict__ x, unsigned short* __restrict__ y, int n4)
{
    int i = blockIdx.x * 256 + threadIdx.x;
    if (i < n4) {
        float4 v = ((const float4*)x)[i];
        ushort4 o = {f2bf(v.x), f2bf(v.y), f2bf(v.z), f2bf(v.w)};
        ((ushort4*)y)[i] = o;
    }
}

// ---------------------------------------------------------------------------
// ktrp: W[kD][nt] f32 -> WT[nt][kD] bf16 (transpose + convert)
// ---------------------------------------------------------------------------
__global__ __launch_bounds__(256)
void ktrp(const float* __restrict__ W, unsigned short* __restrict__ WT, int nt)
{
    __shared__ float T[64][65];
    const int k0 = blockIdx.x * 64;
    const int n0 = blockIdx.y * 64;
    const int c = threadIdx.x & 63, r0 = threadIdx.x >> 6;
    #pragma unroll
    for (int rr = 0; rr < 64; rr += 4)
        T[r0 + rr][c] = W[(size_t)(k0 + r0 + rr) * nt + n0 + c];
    __syncthreads();
    #pragma unroll
    for (int rr = 0; rr < 64; rr += 4)
        WT[(size_t)(n0 + r0 + rr) * kD + k0 + c] = f2bf(T[c][r0 + rr]);
}

// ---------------------------------------------------------------------------
// krepack_w0: W0T[col][k] bf16 -> W0s, k4-tile-major with the conflict-free
// granule permutation baked in. Per K-block kb (32 k's), the 512x32 tile is
// one contiguous 32 KB run of 32 chunks x 1024 B. Granule g of chunk c holds
// (row c*16 + (g&7)+((g>>5)<<3), k-granule (g>>3)&3) -- exactly what k4's
// permuted LDS read (bco) expects when the DMA writes granules linearly.
// ---------------------------------------------------------------------------
__global__ __launch_bounds__(64)
void krepack_w0(const unsigned short* __restrict__ W0T, unsigned short* __restrict__ W0s)
{
    const int kb    = blockIdx.x;   // 0..63  : K-block (32 k's)
    const int chunk = blockIdx.y;   // 0..31  : 16-row chunk
    const int g     = threadIdx.x;  // 0..63  : granule
    const int row = chunk * 16 + (g & 7) + ((g >> 5) << 3);
    const int cg8 = ((g >> 3) & 3) * 8;
    const uint4 v = *(const uint4*)&W0T[(size_t)row * kD + kb * 32 + cg8];
    *(uint4*)&W0s[(size_t)kb * 16384 + chunk * 512 + g * 8] = v;
}

// ---------------------------------------------------------------------------
// K3: ba/bb = box @ Wba/Wbb, K=4 -> elementwise
// ---------------------------------------------------------------------------
__global__ __launch_bounds__(256)
void k3_box_proj(const float* __restrict__ box, const float* __restrict__ Wba,
                 const float* __restrict__ Wbb,
                 float* __restrict__ ba, float* __restrict__ bb)
{
    const int r = blockIdx.y;
    const int c = blockIdx.x * 256 + threadIdx.x;
    const float x0 = box[r * 4 + 0], x1 = box[r * 4 + 1];
    const float x2 = box[r * 4 + 2], x3 = box[r * 4 + 3];
    float va = x0 * Wba[c] + x1 * Wba[kD + c] + x2 * Wba[2 * kD + c] + x3 * Wba[3 * kD + c];
    float vb = x0 * Wbb[c] + x1 * Wbb[kD + c] + x2 * Wbb[2 * kD + c] + x3 * Wbb[3 * kD + c];
    ba[(size_t)r * kD + c] = va;
    bb[(size_t)r * kD + c] = vb;
}

// ---------------------------------------------------------------------------
// Staging helpers for k1/k2: Rx32 bf16 tiles via global_load_lds width=16.
// ---------------------------------------------------------------------------
__device__ inline void stage128(const unsigned short* __restrict__ g,
                                int grow0, int k0,
                                unsigned short* lds, int w, int lane)
{
    const int sr = lane >> 2, sc = (lane & 3) * 8;
    #pragma unroll
    for (int t = 0; t < 2; ++t) {
        int r = w * 32 + t * 16;
        const unsigned short* gp = g + (size_t)(grow0 + r + sr) * kD + k0 + sc;
        __builtin_amdgcn_global_load_lds((glb_u32*)gp, (lds_u32*)(lds + r * 32), 16, 0, 0);
    }
}
__device__ inline void stage64(const unsigned short* __restrict__ g,
                               int grow0, int k0,
                               unsigned short* lds, int w, int lane)
{
    const int sr = lane >> 2, sc = (lane & 3) * 8;
    int r = w * 16;
    const unsigned short* gp = g + (size_t)(grow0 + r + sr) * kD + k0 + sc;
    __builtin_amdgcn_global_load_lds((glb_u32*)gp, (lds_u32*)(lds + r * 32), 16, 0, 0);
}

// ---------------------------------------------------------------------------
// K1 (MFMA dual): fused_bf16 = bf16((Qb @ WqT') .* (Ob @ WoT')), 128x64 tile
// ---------------------------------------------------------------------------
__global__ __launch_bounds__(256, 2)
void k1_dual_mfma(const unsigned short* __restrict__ Qb,
                  const unsigned short* __restrict__ WqT,
                  const unsigned short* __restrict__ Ob,
                  const unsigned short* __restrict__ WoT,
                  unsigned short* __restrict__ fusedb)
{
    __shared__ __align__(16) unsigned short As1[128][32];
    __shared__ __align__(16) unsigned short As2[128][32];
    __shared__ __align__(16) unsigned short Bs1[64][32];
    __shared__ __align__(16) unsigned short Bs2[64][32];

    const int tid = threadIdx.x;
    const int lane = tid & 63;
    const int w = tid >> 6;
    const int wm = w >> 1, wn = w & 1;
    const int row0 = blockIdx.y * 128;
    const int col0 = blockIdx.x * 64;

    f32x4 acc1[4][2], acc2[4][2];
    #pragma unroll
    for (int mt = 0; mt < 4; ++mt)
        #pragma unroll
        for (int nt = 0; nt < 2; ++nt) { acc1[mt][nt] = (f32x4)(0.f); acc2[mt][nt] = (f32x4)(0.f); }

    const int fr = lane & 15, ko = (lane >> 4) * 8;

    for (int k0 = 0; k0 < kD; k0 += 32) {
        stage128(Qb,  row0, k0, &As1[0][0], w, lane);
        stage128(Ob,  row0, k0, &As2[0][0], w, lane);
        stage64 (WqT, col0, k0, &Bs1[0][0], w, lane);
        stage64 (WoT, col0, k0, &Bs2[0][0], w, lane);
        __syncthreads();

        bf16x8 a1[4], a2[4];
        #pragma unroll
        for (int mt = 0; mt < 4; ++mt) {
            a1[mt] = *(bf16x8*)&As1[wm * 64 + mt * 16 + fr][ko];
            a2[mt] = *(bf16x8*)&As2[wm * 64 + mt * 16 + fr][ko];
        }
        #pragma unroll
        for (int nt = 0; nt < 2; ++nt) {
            bf16x8 b1 = *(bf16x8*)&Bs1[wn * 32 + nt * 16 + fr][ko];
            bf16x8 b2 = *(bf16x8*)&Bs2[wn * 32 + nt * 16 + fr][ko];
            #pragma unroll
            for (int mt = 0; mt < 4; ++mt) {
                acc1[mt][nt] = __builtin_amdgcn_mfma_f32_16x16x32_bf16(a1[mt], b1, acc1[mt][nt], 0, 0, 0);
                acc2[mt][nt] = __builtin_amdgcn_mfma_f32_16x16x32_bf16(a2[mt], b2, acc2[mt][nt], 0, 0, 0);
            }
        }
        __syncthreads();
    }

    const int fq = lane >> 4;
    #pragma unroll
    for (int mt = 0; mt < 4; ++mt)
        #pragma unroll
        for (int nt = 0; nt < 2; ++nt) {
            int row = row0 + wm * 64 + mt * 16 + fq * 4;
            int col = col0 + wn * 32 + nt * 16 + fr;
            #pragma unroll
            for (int reg = 0; reg < 4; ++reg) {
                float v = acc1[mt][nt][reg] * acc2[mt][nt][reg];
                fusedb[(size_t)(row + reg) * kD + col] = f2bf(v);
            }
        }
}

// ---------------------------------------------------------------------------
// K2 (MFMA dual-B): ra = Fb @ WfaT', rb = Fb @ WfbT', 128x64 tile
// ---------------------------------------------------------------------------
__global__ __launch_bounds__(256, 2)
void k2_dual_mfma(const unsigned short* __restrict__ Fb,
                  const unsigned short* __restrict__ WfaT,
                  const unsigned short* __restrict__ WfbT,
                  float* __restrict__ ra, float* __restrict__ rb)
{
    __shared__ __align__(16) unsigned short As [128][32];
    __shared__ __align__(16) unsigned short Bs1[64][32];
    __shared__ __align__(16) unsigned short Bs2[64][32];

    const int tid = threadIdx.x;
    const int lane = tid & 63;
    const int w = tid >> 6;
    const int wm = w >> 1, wn = w & 1;
    const int row0 = blockIdx.y * 128;
    const int col0 = blockIdx.x * 64;

    f32x4 acc1[4][2], acc2[4][2];
    #pragma unroll
    for (int mt = 0; mt < 4; ++mt)
        #pragma unroll
        for (int nt = 0; nt < 2; ++nt) { acc1[mt][nt] = (f32x4)(0.f); acc2[mt][nt] = (f32x4)(0.f); }

    const int fr = lane & 15, ko = (lane >> 4) * 8;

    for (int k0 = 0; k0 < kD; k0 += 32) {
        stage128(Fb,   row0, k0, &As [0][0], w, lane);
        stage64 (WfaT, col0, k0, &Bs1[0][0], w, lane);
        stage64 (WfbT, col0, k0, &Bs2[0][0], w, lane);
        __syncthreads();

        bf16x8 a[4];
        #pragma unroll
        for (int mt = 0; mt < 4; ++mt)
            a[mt] = *(bf16x8*)&As[wm * 64 + mt * 16 + fr][ko];
        #pragma unroll
        for (int nt = 0; nt < 2; ++nt) {
            bf16x8 b1 = *(bf16x8*)&Bs1[wn * 32 + nt * 16 + fr][ko];
            bf16x8 b2 = *(bf16x8*)&Bs2[wn * 32 + nt * 16 + fr][ko];
            #pragma unroll
            for (int mt = 0; mt < 4; ++mt) {
                acc1[mt][nt] = __builtin_amdgcn_mfma_f32_16x16x32_bf16(a[mt], b1, acc1[mt][nt], 0, 0, 0);
                acc2[mt][nt] = __builtin_amdgcn_mfma_f32_16x16x32_bf16(a[mt], b2, acc2[mt][nt], 0, 0, 0);
            }
        }
        __syncthreads();
    }

    const int fq = lane >> 4;
    #pragma unroll
    for (int mt = 0; mt < 4; ++mt)
        #pragma unroll
        for (int nt = 0; nt < 2; ++nt) {
            int row = row0 + wm * 64 + mt * 16 + fq * 4;
            int col = col0 + wn * 32 + nt * 16 + fr;
            #pragma unroll
            for (int reg = 0; reg < 4; ++reg) {
                size_t o = (size_t)(row + reg) * kD + col;
                ra[o] = acc1[mt][nt][reg];
                rb[o] = acc2[mt][nt][reg];
            }
        }
}

// ---------------------------------------------------------------------------
// K4 v5: single-barrier software pipeline; conflict-free Bs reads AND fully
// contiguous DMA.
//
// W0s (from krepack_w0) is tile-major with the granule permutation baked in:
// each global_load_lds reads 1024 contiguous bytes (16 sequential full cache
// lines -- max coalescing), writes LDS linearly, and the permuted read
// offset bco makes 16 consecutive fragment rows hit byte starts
// 16*(fr&7)+512*(fr>>3): all 32 banks, exactly 2-way (the b128 floor).
// v4's regression was permuting the DMA *source* (consecutive lanes 4096 B
// apart -> 2x VMEM transactions per DMA, exposed at the barrier at
// 1 block/CU); the permutation now lives in global layout instead.
// ---------------------------------------------------------------------------
__global__ __launch_bounds__(512, 2)
void k4_scores_mfma(const float* __restrict__ ra, const float* __restrict__ rb,
                    const float* __restrict__ ba, const float* __restrict__ bb,
                    const unsigned short* __restrict__ W0s,
                    const float* __restrict__ b0, const float* __restrict__ W1,
                    float* __restrict__ scores)
{
    __shared__ __align__(16) unsigned short Bs[2][512 * 32];  // 64 KB
    __shared__ __align__(16) unsigned short RelS[2][128][40]; // 20 KB
    __shared__ float scoreS[128];

    const int tid  = threadIdx.x;
    const int lane = tid & 63;
    const int w    = tid >> 6;        // 0..7
    const int wm   = w >> 2;          // 0..1 : M-half
    const int wn   = w & 3;           // 0..3 : N-quarter (128 cols)
    const int t0   = blockIdx.x * 128;  // global pair-row tile (all rows valid)

    // A-gen slots: 1024 = 128 rows x 8 col-groups; thread does slots tid, tid+512
    int rowA[2], cgA[2];
    const float *raP[2], *rbP[2], *baP[2], *bbP[2];
    #pragma unroll
    for (int t = 0; t < 2; ++t) {
        int s = tid + t * 512;
        rowA[t] = s >> 3; cgA[t] = s & 7;
        int gp = t0 + rowA[t];
        int b  = gp / kPairs;
        int r  = gp - b * kPairs;
        int i  = r / kN, j = r - i * kN;
        raP[t] = ra + (size_t)(b * kN + i) * kD;
        baP[t] = ba + (size_t)(b * kN + i) * kD;
        rbP[t] = rb + (size_t)(b * kN + j) * kD;
        bbP[t] = bb + (size_t)(b * kN + j) * kD;
    }

    const int fr = lane & 15, fq = lane >> 4;
    // Bs read: per-lane constant part of the permuted short-offset
    const int bco = ((fr & 7) << 3) + ((fr >> 3) << 8) + (fq << 6);

    f32x4 acc[4][8];
    #pragma unroll
    for (int mt = 0; mt < 4; ++mt)
        #pragma unroll
        for (int nt = 0; nt < 8; ++nt)
            acc[mt][nt] = (f32x4)(0.f);

    if (tid < 128) scoreS[tid] = 0.f;

    float4 pa[2], pr[2], pp[2], pq[2];   // prefetched A-gen operands

    #define ISSUE_B(k0_, buf_)                                                   \
        _Pragma("unroll")                                                        \
        for (int t = 0; t < 4; ++t) {                                            \
            int chunk = w * 4 + t;                                               \
            const unsigned short* gp = W0s + (size_t)((k0_) >> 5) * 16384        \
                                       + chunk * 512 + lane * 8;                 \
            __builtin_amdgcn_global_load_lds((glb_u32*)gp,                       \
                (lds_u32*)&Bs[buf_][chunk * 512], 16, 0, 0);                     \
        }

    #define LOAD_A(k0_)                                                          \
        _Pragma("unroll")                                                        \
        for (int t = 0; t < 2; ++t) {                                            \
            pa[t] = *(const float4*)(raP[t] + (k0_) + cgA[t] * 4);               \
            pr[t] = *(const float4*)(rbP[t] + (k0_) + cgA[t] * 4);               \
            pp[t] = *(const float4*)(baP[t] + (k0_) + cgA[t] * 4);               \
            pq[t] = *(const float4*)(bbP[t] + (k0_) + cgA[t] * 4);               \
        }

    #define WRITE_REL(buf_)                                                      \
        _Pragma("unroll")                                                        \
        for (int t = 0; t < 2; ++t) {                                            \
            ushort4 o;                                                           \
            o.x = f2bf(pa[t].x * pr[t].x + pp[t].x * pq[t].x);                   \
            o.y = f2bf(pa[t].y * pr[t].y + pp[t].y * pq[t].y);                   \
            o.z = f2bf(pa[t].z * pr[t].z + pp[t].z * pq[t].z);                   \
            o.w = f2bf(pa[t].w * pr[t].w + pp[t].w * pq[t].w);                   \
            *(ushort4*)&RelS[buf_][rowA[t]][cgA[t] * 4] = o;                     \
        }

    // prologue: fill buffer 0
    LOAD_A(0)
    ISSUE_B(0, 0)
    WRITE_REL(0)

    for (int k0 = 0; k0 < kD; k0 += 32) {
        const int cur = (k0 >> 5) & 1, nxt = cur ^ 1;
        const bool more = (k0 + 32 < kD);
        __syncthreads();   // Bs[cur] DMA drained; RelS[cur] visible
        if (more) {
            LOAD_A(k0 + 32)         // A-regs in flight during MFMA
            ISSUE_B(k0 + 32, nxt)   // DMA runs during this step's MFMA
        }
        bf16x8 af[4];
        #pragma unroll
        for (int mt = 0; mt < 4; ++mt)
            af[mt] = *(bf16x8*)&RelS[cur][wm * 64 + mt * 16 + fr][fq * 8];
        #pragma unroll
        for (int nt = 0; nt < 8; ++nt) {
            bf16x8 bfv = *(bf16x8*)&Bs[cur][wn * 4096 + nt * 512 + bco];
            #pragma unroll
            for (int mt = 0; mt < 4; ++mt)
                acc[mt][nt] = __builtin_amdgcn_mfma_f32_16x16x32_bf16(af[mt], bfv, acc[mt][nt], 0, 0, 0);
        }
        if (more) { WRITE_REL(nxt) }
    }

    // epilogue: score_row = sum_cols W1*tanh(H + b0); b1 softmax-invariant
    float b0v[8], w1v[8];
    #pragma unroll
    for (int nt = 0; nt < 8; ++nt) {
        int col = wn * 128 + nt * 16 + fr;
        b0v[nt] = b0[col];
        w1v[nt] = W1[col];
    }
    #pragma unroll
    for (int mt = 0; mt < 4; ++mt) {
        #pragma unroll
        for (int reg = 0; reg < 4; ++reg) {
            float p = 0.f;
            #pragma unroll
            for (int nt = 0; nt < 8; ++nt)
                p += w1v[nt] * tanhf(acc[mt][nt][reg] + b0v[nt]);
            p += __shfl_xor(p, 1, 64);
            p += __shfl_xor(p, 2, 64);
            p += __shfl_xor(p, 4, 64);
            p += __shfl_xor(p, 8, 64);
            if (fr == 0)
                atomicAdd(&scoreS[wm * 64 + mt * 16 + fq * 4 + reg], p);
        }
    }
    __syncthreads();
    if (tid < 128)
        scores[(size_t)t0 + tid] = scoreS[tid];
}

// ---------------------------------------------------------------------------
// K5: softmax over j
// ---------------------------------------------------------------------------
__global__ __launch_bounds__(64)
void k5_softmax(const float* __restrict__ scores, float* __restrict__ att)
{
    const int bi = blockIdx.x;
    const int tid = threadIdx.x;
    float s = (tid < kN) ? scores[(size_t)bi * kN + tid] : -1e30f;
    float m = s;
    #pragma unroll
    for (int off = 32; off >= 1; off >>= 1)
        m = fmaxf(m, __shfl_xor(m, off, 64));
    float e = (tid < kN) ? expf(s - m) : 0.f;
    float sum = e;
    #pragma unroll
    for (int off = 32; off >= 1; off >>= 1)
        sum += __shfl_xor(sum, off, 64);
    if (tid < kN) att[(size_t)bi * kN + tid] = e / sum;
}

// ---------------------------------------------------------------------------
// K6: out[b,i,:] = obj + fused + ra_i.(att_i @ RB_b) + ba_i.(att_i @ BB_b)
// ---------------------------------------------------------------------------
__global__ __launch_bounds__(256)
void k6_output(const float* __restrict__ obj, const unsigned short* __restrict__ fusedb,
               const float* __restrict__ ra, const float* __restrict__ ba,
               const float* __restrict__ rb, const float* __restrict__ bb,
               const float* __restrict__ att, float* __restrict__ out)
{
    __shared__ float attS[kN];
    const int bi = blockIdx.x;
    const int b = bi / kN;
    const int tid = threadIdx.x;
    if (tid < kN) attS[tid] = att[(size_t)bi * kN + tid];
    __syncthreads();
    for (int d = tid; d < kD; d += 256) {
        float s1 = 0.f, s2 = 0.f;
        #pragma unroll 4
        for (int j = 0; j < kN; ++j) {
            float a = attS[j];
            size_t rrow = (size_t)(b * kN + j) * kD + d;
            s1 = fmaf(a, rb[rrow], s1);
            s2 = fmaf(a, bb[rrow], s2);
        }
        size_t o = (size_t)bi * kD + d;
        float fv = __uint_as_float((u32)fusedb[o] << 16);
        out[o] = obj[o] + fv + ra[o] * s1 + ba[o] * s2;
    }
}

// ---------------------------------------------------------------------------
extern "C" void kernel_launch(void* const* d_in, const int* in_sizes, int n_in,
                              void* d_out, int out_size, void* d_ws, size_t ws_size,
                              hipStream_t stream)
{
    const float* q   = (const float*)d_in[0];
    const float* obj = (const float*)d_in[1];
    const float* box = (const float*)d_in[2];
    const float* Wq  = (const float*)d_in[3];
    const float* Wo  = (const float*)d_in[4];
    const float* Wfa = (const float*)d_in[5];
    const float* Wfb = (const float*)d_in[6];
    const float* Wba = (const float*)d_in[7];
    const float* Wbb = (const float*)d_in[8];
    const float* W0  = (const float*)d_in[9];
    const float* b0v = (const float*)d_in[10];
    const float* W1  = (const float*)d_in[11];
    // d_in[12] = b1 (softmax-invariant), d_in[13..14] scalars: unused
    float* out = (float*)d_out;

    const size_t nBD = (size_t)kBN * kD;
    float* ws = (float*)d_ws;
    size_t off = 0;
    float* ra     = ws + off; off += nBD;
    float* rb     = ws + off; off += nBD;
    float* ba     = ws + off; off += nBD;
    float* bb     = ws + off; off += nBD;
    float* scores = ws + off; off += (size_t)kBN * kN;
    float* att    = ws + off; off += (size_t)kBN * kN;

    unsigned short* us = (unsigned short*)(ws + off);
    size_t uoff = 0;
    unsigned short* W0T     = us + uoff; uoff += (size_t)kDatt * kD;
    unsigned short* W0s     = us + uoff; uoff += (size_t)kDatt * kD;
    unsigned short* q_bf    = us + uoff; uoff += nBD;
    unsigned short* obj_bf  = us + uoff; uoff += nBD;
    unsigned short* fusedbf = us + uoff; uoff += nBD;
    unsigned short* WqT     = us + uoff; uoff += (size_t)kD * kD;
    unsigned short* WoT     = us + uoff; uoff += (size_t)kD * kD;
    // WfaT/WfbT alias q_bf/obj_bf (dead after k1; stream order guarantees safety)
    unsigned short* WfaT = q_bf;
    unsigned short* WfbT = obj_bf;

    const int n4 = (int)(nBD / 4);
    kcvt<<<dim3((n4 + 255) / 256), 256, 0, stream>>>(q,   q_bf,   n4);
    kcvt<<<dim3((n4 + 255) / 256), 256, 0, stream>>>(obj, obj_bf, n4);
    ktrp<<<dim3(32, 32), 256, 0, stream>>>(Wq, WqT, kD);
    ktrp<<<dim3(32, 32), 256, 0, stream>>>(Wo, WoT, kD);
    ktrp<<<dim3(32, 8),  256, 0, stream>>>(W0, W0T, kDatt);
    krepack_w0<<<dim3(kD / 32, kDatt / 16), 64, 0, stream>>>(W0T, W0s);
    k3_box_proj<<<dim3(kD / 256, kBN), 256, 0, stream>>>(box, Wba, Wbb, ba, bb);

    k1_dual_mfma<<<dim3(kD / 64, kBN / 128), 256, 0, stream>>>(q_bf, WqT, obj_bf, WoT, fusedbf);

    ktrp<<<dim3(32, 32), 256, 0, stream>>>(Wfa, WfaT, kD);
    ktrp<<<dim3(32, 32), 256, 0, stream>>>(Wfb, WfbT, kD);

    k2_dual_mfma<<<dim3(kD / 64, kBN / 128), 256, 0, stream>>>(fusedbf, WfaT, WfbT, ra, rb);

    k4_scores_mfma<<<dim3(kRows / 128), 512, 0, stream>>>(ra, rb, ba, bb, W0s, b0v, W1, scores);
    k5_softmax<<<kBN, 64, 0, stream>>>(scores, att);
    k6_output<<<kBN, 256, 0, stream>>>(obj, fusedbf, ra, ba, rb, bb, att, out);
}

// Round 3
// 712.827 us; speedup vs baseline: 1.2010x; 1.0459x over previous
//
#include <hip/hip_runtime.h>
#include <hip/hip_bf16.h>
#include <math.h>

constexpr int kB    = 64;
constexpr int kN    = 36;
constexpr int kBN   = kB * kN;   // 2304
constexpr int kD    = 2048;
constexpr int kDatt = 512;
constexpr int kPairs = kN * kN;  // 1296

using bf16x8 = __attribute__((ext_vector_type(8))) short;
using f32x4  = __attribute__((ext_vector_type(4))) float;

typedef unsigned int u32;
typedef __attribute__((address_space(3))) u32 lds_u32;
typedef const __attribute__((address_space(1))) u32 glb_u32;

__device__ inline unsigned short f2bf(float f) {
    union { float f; unsigned u; } v; v.f = f;
    unsigned r = v.u + 0x7FFFu + ((v.u >> 16) & 1u);   // RNE
    return (unsigned short)(r >> 16);
}

// ---------------------------------------------------------------------------
// kcvt: f32 -> bf16 elementwise
// ---------------------------------------------------------------------------
__global__ __launch_bounds__(256)
void kcvt(const float* __restrict__ x, unsigned short* __restrict__ y, int n4)
{
    int i = blockIdx.x * 256 + threadIdx.x;
    if (i < n4) {
        float4 v = ((const float4*)x)[i];
        ushort4 o = {f2bf(v.x), f2bf(v.y), f2bf(v.z), f2bf(v.w)};
        ((ushort4*)y)[i] = o;
    }
}

// ---------------------------------------------------------------------------
// ktrp: W[kD][nt] f32 -> WT[nt][kD] bf16 (transpose + convert)
// ---------------------------------------------------------------------------
__global__ __launch_bounds__(256)
void ktrp(const float* __restrict__ W, unsigned short* __restrict__ WT, int nt)
{
    __shared__ float T[64][65];
    const int k0 = blockIdx.x * 64;
    const int n0 = blockIdx.y * 64;
    const int c = threadIdx.x & 63, r0 = threadIdx.x >> 6;
    #pragma unroll
    for (int rr = 0; rr < 64; rr += 4)
        T[r0 + rr][c] = W[(size_t)(k0 + r0 + rr) * nt + n0 + c];
    __syncthreads();
    #pragma unroll
    for (int rr = 0; rr < 64; rr += 4)
        WT[(size_t)(n0 + r0 + rr) * kD + k0 + c] = f2bf(T[c][r0 + rr]);
}

// ---------------------------------------------------------------------------
// krepack_w0: W0T[col][k] bf16 -> W0s, k4-tile-major with the conflict-free
// granule permutation baked in (see v5 header).
// ---------------------------------------------------------------------------
__global__ __launch_bounds__(64)
void krepack_w0(const unsigned short* __restrict__ W0T, unsigned short* __restrict__ W0s)
{
    const int kb    = blockIdx.x;   // 0..63  : K-block (32 k's)
    const int chunk = blockIdx.y;   // 0..31  : 16-row chunk
    const int g     = threadIdx.x;  // 0..63  : granule
    const int row = chunk * 16 + (g & 7) + ((g >> 5) << 3);
    const int cg8 = ((g >> 3) & 3) * 8;
    const uint4 v = *(const uint4*)&W0T[(size_t)row * kD + kb * 32 + cg8];
    *(uint4*)&W0s[(size_t)kb * 16384 + chunk * 512 + g * 8] = v;
}

// ---------------------------------------------------------------------------
// K3: ba/bb = box @ Wba/Wbb, K=4 -> elementwise
// ---------------------------------------------------------------------------
__global__ __launch_bounds__(256)
void k3_box_proj(const float* __restrict__ box, const float* __restrict__ Wba,
                 const float* __restrict__ Wbb,
                 float* __restrict__ ba, float* __restrict__ bb)
{
    const int r = blockIdx.y;
    const int c = blockIdx.x * 256 + threadIdx.x;
    const float x0 = box[r * 4 + 0], x1 = box[r * 4 + 1];
    const float x2 = box[r * 4 + 2], x3 = box[r * 4 + 3];
    float va = x0 * Wba[c] + x1 * Wba[kD + c] + x2 * Wba[2 * kD + c] + x3 * Wba[3 * kD + c];
    float vb = x0 * Wbb[c] + x1 * Wbb[kD + c] + x2 * Wbb[2 * kD + c] + x3 * Wbb[3 * kD + c];
    ba[(size_t)r * kD + c] = va;
    bb[(size_t)r * kD + c] = vb;
}

// ---------------------------------------------------------------------------
// Staging helpers for k1/k2: Rx32 bf16 tiles via global_load_lds width=16.
// ---------------------------------------------------------------------------
__device__ inline void stage128(const unsigned short* __restrict__ g,
                                int grow0, int k0,
                                unsigned short* lds, int w, int lane)
{
    const int sr = lane >> 2, sc = (lane & 3) * 8;
    #pragma unroll
    for (int t = 0; t < 2; ++t) {
        int r = w * 32 + t * 16;
        const unsigned short* gp = g + (size_t)(grow0 + r + sr) * kD + k0 + sc;
        __builtin_amdgcn_global_load_lds((glb_u32*)gp, (lds_u32*)(lds + r * 32), 16, 0, 0);
    }
}
__device__ inline void stage64(const unsigned short* __restrict__ g,
                               int grow0, int k0,
                               unsigned short* lds, int w, int lane)
{
    const int sr = lane >> 2, sc = (lane & 3) * 8;
    int r = w * 16;
    const unsigned short* gp = g + (size_t)(grow0 + r + sr) * kD + k0 + sc;
    __builtin_amdgcn_global_load_lds((glb_u32*)gp, (lds_u32*)(lds + r * 32), 16, 0, 0);
}

// ---------------------------------------------------------------------------
// K1 (MFMA dual): fused_bf16 = bf16((Qb @ WqT') .* (Ob @ WoT')), 128x64 tile
// ---------------------------------------------------------------------------
__global__ __launch_bounds__(256, 2)
void k1_dual_mfma(const unsigned short* __restrict__ Qb,
                  const unsigned short* __restrict__ WqT,
                  const unsigned short* __restrict__ Ob,
                  const unsigned short* __restrict__ WoT,
                  unsigned short* __restrict__ fusedb)
{
    __shared__ __align__(16) unsigned short As1[128][32];
    __shared__ __align__(16) unsigned short As2[128][32];
    __shared__ __align__(16) unsigned short Bs1[64][32];
    __shared__ __align__(16) unsigned short Bs2[64][32];

    const int tid = threadIdx.x;
    const int lane = tid & 63;
    const int w = tid >> 6;
    const int wm = w >> 1, wn = w & 1;
    const int row0 = blockIdx.y * 128;
    const int col0 = blockIdx.x * 64;

    f32x4 acc1[4][2], acc2[4][2];
    #pragma unroll
    for (int mt = 0; mt < 4; ++mt)
        #pragma unroll
        for (int nt = 0; nt < 2; ++nt) { acc1[mt][nt] = (f32x4)(0.f); acc2[mt][nt] = (f32x4)(0.f); }

    const int fr = lane & 15, ko = (lane >> 4) * 8;

    for (int k0 = 0; k0 < kD; k0 += 32) {
        stage128(Qb,  row0, k0, &As1[0][0], w, lane);
        stage128(Ob,  row0, k0, &As2[0][0], w, lane);
        stage64 (WqT, col0, k0, &Bs1[0][0], w, lane);
        stage64 (WoT, col0, k0, &Bs2[0][0], w, lane);
        __syncthreads();

        bf16x8 a1[4], a2[4];
        #pragma unroll
        for (int mt = 0; mt < 4; ++mt) {
            a1[mt] = *(bf16x8*)&As1[wm * 64 + mt * 16 + fr][ko];
            a2[mt] = *(bf16x8*)&As2[wm * 64 + mt * 16 + fr][ko];
        }
        #pragma unroll
        for (int nt = 0; nt < 2; ++nt) {
            bf16x8 b1 = *(bf16x8*)&Bs1[wn * 32 + nt * 16 + fr][ko];
            bf16x8 b2 = *(bf16x8*)&Bs2[wn * 32 + nt * 16 + fr][ko];
            #pragma unroll
            for (int mt = 0; mt < 4; ++mt) {
                acc1[mt][nt] = __builtin_amdgcn_mfma_f32_16x16x32_bf16(a1[mt], b1, acc1[mt][nt], 0, 0, 0);
                acc2[mt][nt] = __builtin_amdgcn_mfma_f32_16x16x32_bf16(a2[mt], b2, acc2[mt][nt], 0, 0, 0);
            }
        }
        __syncthreads();
    }

    const int fq = lane >> 4;
    #pragma unroll
    for (int mt = 0; mt < 4; ++mt)
        #pragma unroll
        for (int nt = 0; nt < 2; ++nt) {
            int row = row0 + wm * 64 + mt * 16 + fq * 4;
            int col = col0 + wn * 32 + nt * 16 + fr;
            #pragma unroll
            for (int reg = 0; reg < 4; ++reg) {
                float v = acc1[mt][nt][reg] * acc2[mt][nt][reg];
                fusedb[(size_t)(row + reg) * kD + col] = f2bf(v);
            }
        }
}

// ---------------------------------------------------------------------------
// K2 (MFMA dual-B): ra = Fb @ WfaT', rb = Fb @ WfbT', 128x64 tile
// ---------------------------------------------------------------------------
__global__ __launch_bounds__(256, 2)
void k2_dual_mfma(const unsigned short* __restrict__ Fb,
                  const unsigned short* __restrict__ WfaT,
                  const unsigned short* __restrict__ WfbT,
                  float* __restrict__ ra, float* __restrict__ rb)
{
    __shared__ __align__(16) unsigned short As [128][32];
    __shared__ __align__(16) unsigned short Bs1[64][32];
    __shared__ __align__(16) unsigned short Bs2[64][32];

    const int tid = threadIdx.x;
    const int lane = tid & 63;
    const int w = tid >> 6;
    const int wm = w >> 1, wn = w & 1;
    const int row0 = blockIdx.y * 128;
    const int col0 = blockIdx.x * 64;

    f32x4 acc1[4][2], acc2[4][2];
    #pragma unroll
    for (int mt = 0; mt < 4; ++mt)
        #pragma unroll
        for (int nt = 0; nt < 2; ++nt) { acc1[mt][nt] = (f32x4)(0.f); acc2[mt][nt] = (f32x4)(0.f); }

    const int fr = lane & 15, ko = (lane >> 4) * 8;

    for (int k0 = 0; k0 < kD; k0 += 32) {
        stage128(Fb,   row0, k0, &As [0][0], w, lane);
        stage64 (WfaT, col0, k0, &Bs1[0][0], w, lane);
        stage64 (WfbT, col0, k0, &Bs2[0][0], w, lane);
        __syncthreads();

        bf16x8 a[4];
        #pragma unroll
        for (int mt = 0; mt < 4; ++mt)
            a[mt] = *(bf16x8*)&As[wm * 64 + mt * 16 + fr][ko];
        #pragma unroll
        for (int nt = 0; nt < 2; ++nt) {
            bf16x8 b1 = *(bf16x8*)&Bs1[wn * 32 + nt * 16 + fr][ko];
            bf16x8 b2 = *(bf16x8*)&Bs2[wn * 32 + nt * 16 + fr][ko];
            #pragma unroll
            for (int mt = 0; mt < 4; ++mt) {
                acc1[mt][nt] = __builtin_amdgcn_mfma_f32_16x16x32_bf16(a[mt], b1, acc1[mt][nt], 0, 0, 0);
                acc2[mt][nt] = __builtin_amdgcn_mfma_f32_16x16x32_bf16(a[mt], b2, acc2[mt][nt], 0, 0, 0);
            }
        }
        __syncthreads();
    }

    const int fq = lane >> 4;
    #pragma unroll
    for (int mt = 0; mt < 4; ++mt)
        #pragma unroll
        for (int nt = 0; nt < 2; ++nt) {
            int row = row0 + wm * 64 + mt * 16 + fq * 4;
            int col = col0 + wn * 32 + nt * 16 + fr;
            #pragma unroll
            for (int reg = 0; reg < 4; ++reg) {
                size_t o = (size_t)(row + reg) * kD + col;
                ra[o] = acc1[mt][nt][reg];
                rb[o] = acc2[mt][nt][reg];
            }
        }
}

// ---------------------------------------------------------------------------
// K4 v6: LDS-staged A-operands.
//
// v5 bottleneck: LOAD_A re-read 64 KB f32 of ra/rb/ba/bb per block-K-step
// (2.65 GB aggregate through L3 at ~17 B/cyc/CU ~ 3700 cyc/K-step). But the
// DISTINCT data per K-step is only <=5 i-slices + 36 j-slices x 2 arrays
// ~ 10.75 KB. v6 stages those distinct slices in double-buffered LDS (Stg)
// and Rel-gen reads operands from LDS (6x less global A-traffic).
//
// Pipeline per step k (one barrier): consume RelS[k&1], Bs[k&1];
//   STAGE_LOAD k+2 -> regs; ISSUE_B k+1 -> Bs[(k+1)&1]; MFMA;
//   STAGE_WRITE regs -> Stg[k&1] (= step k+2's buffer);
//   REL_GEN RelS[(k+1)&1] <- Stg[(k+1)&1] (written at step k-1).
// All cross-thread hazards are separated by the per-step barrier.
//
// Grid: per-b tiles (64 b x 11 tiles of 128 pairs; tile 10 has 16 valid
// rows, garbage rows clamped+unstored). XCD-chunked swizzle (704 = 8*88)
// keeps each b's 1.15 MB A-row working set in one XCD's L2.
// Stg rows padded to 17 float4 (68 floats) to spread j-row bank starts.
// ---------------------------------------------------------------------------
__global__ __launch_bounds__(512, 2)
void k4_scores_mfma(const float* __restrict__ ra, const float* __restrict__ rb,
                    const float* __restrict__ ba, const float* __restrict__ bb,
                    const unsigned short* __restrict__ W0s,
                    const float* __restrict__ b0, const float* __restrict__ W1,
                    float* __restrict__ scores)
{
    __shared__ __align__(16) unsigned short Bs[2][512 * 32];  // 64 KB
    __shared__ __align__(16) unsigned short RelS[2][128][40]; // 20 KB
    __shared__ __align__(16) float4 Stg4[2][714];             // 22.3 KB : 42 rows x 17 f4
    __shared__ float scoreS[128];

    const int tid  = threadIdx.x;
    const int lane = tid & 63;
    const int w    = tid >> 6;        // 0..7
    const int wm   = w >> 2;          // 0..1 : M-half
    const int wn   = w & 3;           // 0..3 : N-quarter (128 cols)

    // XCD-chunked swizzle: 704 = 8 XCDs x 88; same-b tiles stay on one XCD
    const int work = (blockIdx.x & 7) * 88 + (blockIdx.x >> 3);
    const int b    = work / 11;
    const int tile = work - b * 11;   // 0..10 (tile 10: 16 valid rows)
    const int p0   = tile * 128;      // first pair index within b
    const int i0   = p0 / kN;

    const float* raB = ra + (size_t)b * kN * kD;
    const float* rbB = rb + (size_t)b * kN * kD;
    const float* baB = ba + (size_t)b * kN * kD;
    const float* bbB = bb + (size_t)b * kN * kD;

    // ---- stage slots: 672 = 42 rows x 16 f4 (rows 0..5 = i-rows ra/ba,
    //      rows 6..41 = j-rows rb/bb; per row: f4 0..7 = arr0, 8..15 = arr1)
    const bool has2 = (tid < 160);
    const float* sptr[2];
    int sdst[2];
    #pragma unroll
    for (int t = 0; t < 2; ++t) {
        int s = tid + t * 512; if (s > 671) s = 671;
        int row = s >> 4, t4 = s & 15;
        int arr = t4 >> 3, q = t4 & 7;
        int grow; const float* base;
        if (row < 6) {
            int il = (row < 5) ? row : 4;
            grow = i0 + il; if (grow > kN - 1) grow = kN - 1;
            base = arr ? baB : raB;
        } else {
            grow = row - 6;
            base = arr ? bbB : rbB;
        }
        sptr[t] = base + (size_t)grow * kD + q * 4;
        sdst[t] = row * 17 + t4;
    }

    // ---- Rel-gen slots: 1024 = 128 rows x 8 col-groups; thread does 2
    int rowA[2], cgA[2], ilA[2], jA[2];
    #pragma unroll
    for (int t = 0; t < 2; ++t) {
        int s = tid + t * 512;
        rowA[t] = s >> 3; cgA[t] = s & 7;
        int p = p0 + rowA[t]; if (p >= kPairs) p = kPairs - 1;
        int i = p / kN;
        jA[t]  = p - i * kN;
        ilA[t] = i - i0;
    }

    const int fr = lane & 15, fq = lane >> 4;
    const int bco = ((fr & 7) << 3) + ((fr >> 3) << 8) + (fq << 6);

    f32x4 acc[4][8];
    #pragma unroll
    for (int mt = 0; mt < 4; ++mt)
        #pragma unroll
        for (int nt = 0; nt < 8; ++nt)
            acc[mt][nt] = (f32x4)(0.f);

    if (tid < 128) scoreS[tid] = 0.f;

    float4 sreg0, sreg1;

    #define ISSUE_B(k0_, buf_)                                                   \
        _Pragma("unroll")                                                        \
        for (int t = 0; t < 4; ++t) {                                            \
            int chunk = w * 4 + t;                                               \
            const unsigned short* gp = W0s + (size_t)((k0_) >> 5) * 16384        \
                                       + chunk * 512 + lane * 8;                 \
            __builtin_amdgcn_global_load_lds((glb_u32*)gp,                       \
                (lds_u32*)&Bs[buf_][chunk * 512], 16, 0, 0);                     \
        }

    #define STAGE_LOAD(k0_) {                                                    \
            sreg0 = *(const float4*)(sptr[0] + (k0_));                           \
            if (has2) sreg1 = *(const float4*)(sptr[1] + (k0_));                 \
        }

    #define STAGE_WRITE(buf_) {                                                  \
            Stg4[buf_][sdst[0]] = sreg0;                                         \
            if (has2) Stg4[buf_][sdst[1]] = sreg1;                               \
        }

    #define REL_GEN(buf_)                                                        \
        _Pragma("unroll")                                                        \
        for (int t = 0; t < 2; ++t) {                                            \
            float4 va = Stg4[buf_][ilA[t] * 17 + cgA[t]];                        \
            float4 vb = Stg4[buf_][ilA[t] * 17 + 8 + cgA[t]];                    \
            float4 vr = Stg4[buf_][(6 + jA[t]) * 17 + cgA[t]];                   \
            float4 vq = Stg4[buf_][(6 + jA[t]) * 17 + 8 + cgA[t]];               \
            ushort4 o;                                                           \
            o.x = f2bf(va.x * vr.x + vb.x * vq.x);                               \
            o.y = f2bf(va.y * vr.y + vb.y * vq.y);                               \
            o.z = f2bf(va.z * vr.z + vb.z * vq.z);                               \
            o.w = f2bf(va.w * vr.w + vb.w * vq.w);                               \
            *(ushort4*)&RelS[buf_][rowA[t]][cgA[t] * 4] = o;                     \
        }

    // ---- prologue: RelS[0], Stg[1], Bs[0]
    STAGE_LOAD(0)
    STAGE_WRITE(0)
    STAGE_LOAD(32)
    __syncthreads();          // Stg[0] visible
    REL_GEN(0)
    STAGE_WRITE(1)
    ISSUE_B(0, 0)

    for (int k = 0; k < 64; ++k) {
        const int cur = k & 1, nxt = cur ^ 1;
        __syncthreads();      // Bs[cur] drained; RelS[cur], Stg[nxt] visible
        if (k < 62) STAGE_LOAD((k + 2) * 32)
        if (k < 63) ISSUE_B((k + 1) * 32, nxt)
        bf16x8 af[4];
        #pragma unroll
        for (int mt = 0; mt < 4; ++mt)
            af[mt] = *(bf16x8*)&RelS[cur][wm * 64 + mt * 16 + fr][fq * 8];
        #pragma unroll
        for (int nt = 0; nt < 8; ++nt) {
            bf16x8 bfv = *(bf16x8*)&Bs[cur][wn * 4096 + nt * 512 + bco];
            #pragma unroll
            for (int mt = 0; mt < 4; ++mt)
                acc[mt][nt] = __builtin_amdgcn_mfma_f32_16x16x32_bf16(af[mt], bfv, acc[mt][nt], 0, 0, 0);
        }
        if (k < 62) STAGE_WRITE(cur)   // step k+2's data into Stg[k&1]
        if (k < 63) REL_GEN(nxt)       // RelS[(k+1)&1] from Stg[(k+1)&1]
    }

    // epilogue: score_row = sum_cols W1*tanh(H + b0); b1 softmax-invariant
    float b0v[8], w1v[8];
    #pragma unroll
    for (int nt = 0; nt < 8; ++nt) {
        int col = wn * 128 + nt * 16 + fr;
        b0v[nt] = b0[col];
        w1v[nt] = W1[col];
    }
    #pragma unroll
    for (int mt = 0; mt < 4; ++mt) {
        #pragma unroll
        for (int reg = 0; reg < 4; ++reg) {
            float p = 0.f;
            #pragma unroll
            for (int nt = 0; nt < 8; ++nt)
                p += w1v[nt] * tanhf(acc[mt][nt][reg] + b0v[nt]);
            p += __shfl_xor(p, 1, 64);
            p += __shfl_xor(p, 2, 64);
            p += __shfl_xor(p, 4, 64);
            p += __shfl_xor(p, 8, 64);
            if (fr == 0)
                atomicAdd(&scoreS[wm * 64 + mt * 16 + fq * 4 + reg], p);
        }
    }
    __syncthreads();
    if (tid < 128 && p0 + tid < kPairs)
        scores[(size_t)b * kPairs + p0 + tid] = scoreS[tid];
}

// ---------------------------------------------------------------------------
// K5: softmax over j
// ---------------------------------------------------------------------------
__global__ __launch_bounds__(64)
void k5_softmax(const float* __restrict__ scores, float* __restrict__ att)
{
    const int bi = blockIdx.x;
    const int tid = threadIdx.x;
    float s = (tid < kN) ? scores[(size_t)bi * kN + tid] : -1e30f;
    float m = s;
    #pragma unroll
    for (int off = 32; off >= 1; off >>= 1)
        m = fmaxf(m, __shfl_xor(m, off, 64));
    float e = (tid < kN) ? expf(s - m) : 0.f;
    float sum = e;
    #pragma unroll
    for (int off = 32; off >= 1; off >>= 1)
        sum += __shfl_xor(sum, off, 64);
    if (tid < kN) att[(size_t)bi * kN + tid] = e / sum;
}

// ---------------------------------------------------------------------------
// K6: out[b,i,:] = obj + fused + ra_i.(att_i @ RB_b) + ba_i.(att_i @ BB_b)
// ---------------------------------------------------------------------------
__global__ __launch_bounds__(256)
void k6_output(const float* __restrict__ obj, const unsigned short* __restrict__ fusedb,
               const float* __restrict__ ra, const float* __restrict__ ba,
               const float* __restrict__ rb, const float* __restrict__ bb,
               const float* __restrict__ att, float* __restrict__ out)
{
    __shared__ float attS[kN];
    const int bi = blockIdx.x;
    const int b = bi / kN;
    const int tid = threadIdx.x;
    if (tid < kN) attS[tid] = att[(size_t)bi * kN + tid];
    __syncthreads();
    for (int d = tid; d < kD; d += 256) {
        float s1 = 0.f, s2 = 0.f;
        #pragma unroll 4
        for (int j = 0; j < kN; ++j) {
            float a = attS[j];
            size_t rrow = (size_t)(b * kN + j) * kD + d;
            s1 = fmaf(a, rb[rrow], s1);
            s2 = fmaf(a, bb[rrow], s2);
        }
        size_t o = (size_t)bi * kD + d;
        float fv = __uint_as_float((u32)fusedb[o] << 16);
        out[o] = obj[o] + fv + ra[o] * s1 + ba[o] * s2;
    }
}

// ---------------------------------------------------------------------------
extern "C" void kernel_launch(void* const* d_in, const int* in_sizes, int n_in,
                              void* d_out, int out_size, void* d_ws, size_t ws_size,
                              hipStream_t stream)
{
    const float* q   = (const float*)d_in[0];
    const float* obj = (const float*)d_in[1];
    const float* box = (const float*)d_in[2];
    const float* Wq  = (const float*)d_in[3];
    const float* Wo  = (const float*)d_in[4];
    const float* Wfa = (const float*)d_in[5];
    const float* Wfb = (const float*)d_in[6];
    const float* Wba = (const float*)d_in[7];
    const float* Wbb = (const float*)d_in[8];
    const float* W0  = (const float*)d_in[9];
    const float* b0v = (const float*)d_in[10];
    const float* W1  = (const float*)d_in[11];
    // d_in[12] = b1 (softmax-invariant), d_in[13..14] scalars: unused
    float* out = (float*)d_out;

    const size_t nBD = (size_t)kBN * kD;
    float* ws = (float*)d_ws;
    size_t off = 0;
    float* ra     = ws + off; off += nBD;
    float* rb     = ws + off; off += nBD;
    float* ba     = ws + off; off += nBD;
    float* bb     = ws + off; off += nBD;
    float* scores = ws + off; off += (size_t)kBN * kN;
    float* att    = ws + off; off += (size_t)kBN * kN;

    unsigned short* us = (unsigned short*)(ws + off);
    size_t uoff = 0;
    unsigned short* W0T     = us + uoff; uoff += (size_t)kDatt * kD;
    unsigned short* W0s     = us + uoff; uoff += (size_t)kDatt * kD;
    unsigned short* q_bf    = us + uoff; uoff += nBD;
    unsigned short* obj_bf  = us + uoff; uoff += nBD;
    unsigned short* fusedbf = us + uoff; uoff += nBD;
    unsigned short* WqT     = us + uoff; uoff += (size_t)kD * kD;
    unsigned short* WoT     = us + uoff; uoff += (size_t)kD * kD;
    // WfaT/WfbT alias q_bf/obj_bf (dead after k1; stream order guarantees safety)
    unsigned short* WfaT = q_bf;
    unsigned short* WfbT = obj_bf;

    const int n4 = (int)(nBD / 4);
    kcvt<<<dim3((n4 + 255) / 256), 256, 0, stream>>>(q,   q_bf,   n4);
    kcvt<<<dim3((n4 + 255) / 256), 256, 0, stream>>>(obj, obj_bf, n4);
    ktrp<<<dim3(32, 32), 256, 0, stream>>>(Wq, WqT, kD);
    ktrp<<<dim3(32, 32), 256, 0, stream>>>(Wo, WoT, kD);
    ktrp<<<dim3(32, 8),  256, 0, stream>>>(W0, W0T, kDatt);
    krepack_w0<<<dim3(kD / 32, kDatt / 16), 64, 0, stream>>>(W0T, W0s);
    k3_box_proj<<<dim3(kD / 256, kBN), 256, 0, stream>>>(box, Wba, Wbb, ba, bb);

    k1_dual_mfma<<<dim3(kD / 64, kBN / 128), 256, 0, stream>>>(q_bf, WqT, obj_bf, WoT, fusedbf);

    ktrp<<<dim3(32, 32), 256, 0, stream>>>(Wfa, WfaT, kD);
    ktrp<<<dim3(32, 32), 256, 0, stream>>>(Wfb, WfbT, kD);

    k2_dual_mfma<<<dim3(kD / 64, kBN / 128), 256, 0, stream>>>(fusedbf, WfaT, WfbT, ra, rb);

    k4_scores_mfma<<<dim3(kB * 11), 512, 0, stream>>>(ra, rb, ba, bb, W0s, b0v, W1, scores);
    k5_softmax<<<kBN, 64, 0, stream>>>(scores, att);
    k6_output<<<kBN, 256, 0, stream>>>(obj, fusedbf, ra, ba, rb, bb, att, out);
}

// Round 4
// 666.376 us; speedup vs baseline: 1.2847x; 1.0697x over previous
//
#include <hip/hip_runtime.h>
#include <hip/hip_bf16.h>
#include <math.h>

constexpr int kB    = 64;
constexpr int kN    = 36;
constexpr int kBN   = kB * kN;   // 2304
constexpr int kD    = 2048;
constexpr int kDatt = 512;
constexpr int kPairs = kN * kN;  // 1296

using bf16x8 = __attribute__((ext_vector_type(8))) short;
using f32x4  = __attribute__((ext_vector_type(4))) float;

typedef unsigned int u32;
typedef __attribute__((address_space(3))) u32 lds_u32;
typedef const __attribute__((address_space(1))) u32 glb_u32;

__device__ inline unsigned short f2bf(float f) {
    union { float f; unsigned u; } v; v.f = f;
    unsigned r = v.u + 0x7FFFu + ((v.u >> 16) & 1u);   // RNE
    return (unsigned short)(r >> 16);
}

// ---------------------------------------------------------------------------
// kcvt: f32 -> bf16 elementwise
// ---------------------------------------------------------------------------
__global__ __launch_bounds__(256)
void kcvt(const float* __restrict__ x, unsigned short* __restrict__ y, int n4)
{
    int i = blockIdx.x * 256 + threadIdx.x;
    if (i < n4) {
        float4 v = ((const float4*)x)[i];
        ushort4 o = {f2bf(v.x), f2bf(v.y), f2bf(v.z), f2bf(v.w)};
        ((ushort4*)y)[i] = o;
    }
}

// ---------------------------------------------------------------------------
// ktrp: W[kD][nt] f32 -> WT[nt][kD] bf16 (transpose + convert)
// ---------------------------------------------------------------------------
__global__ __launch_bounds__(256)
void ktrp(const float* __restrict__ W, unsigned short* __restrict__ WT, int nt)
{
    __shared__ float T[64][65];
    const int k0 = blockIdx.x * 64;
    const int n0 = blockIdx.y * 64;
    const int c = threadIdx.x & 63, r0 = threadIdx.x >> 6;
    #pragma unroll
    for (int rr = 0; rr < 64; rr += 4)
        T[r0 + rr][c] = W[(size_t)(k0 + r0 + rr) * nt + n0 + c];
    __syncthreads();
    #pragma unroll
    for (int rr = 0; rr < 64; rr += 4)
        WT[(size_t)(n0 + r0 + rr) * kD + k0 + c] = f2bf(T[c][r0 + rr]);
}

// ---------------------------------------------------------------------------
// krepack_w0: W0T[col][k] bf16 -> W0s, k4-tile-major with the conflict-free
// granule permutation baked in (see k4 header).
// ---------------------------------------------------------------------------
__global__ __launch_bounds__(64)
void krepack_w0(const unsigned short* __restrict__ W0T, unsigned short* __restrict__ W0s)
{
    const int kb    = blockIdx.x;   // 0..63  : K-block (32 k's)
    const int chunk = blockIdx.y;   // 0..31  : 16-row chunk
    const int g     = threadIdx.x;  // 0..63  : granule
    const int row = chunk * 16 + (g & 7) + ((g >> 5) << 3);
    const int cg8 = ((g >> 3) & 3) * 8;
    const uint4 v = *(const uint4*)&W0T[(size_t)row * kD + kb * 32 + cg8];
    *(uint4*)&W0s[(size_t)kb * 16384 + chunk * 512 + g * 8] = v;
}

// ---------------------------------------------------------------------------
// K3: ba/bb = box @ Wba/Wbb, K=4 -> elementwise
// ---------------------------------------------------------------------------
__global__ __launch_bounds__(256)
void k3_box_proj(const float* __restrict__ box, const float* __restrict__ Wba,
                 const float* __restrict__ Wbb,
                 float* __restrict__ ba, float* __restrict__ bb)
{
    const int r = blockIdx.y;
    const int c = blockIdx.x * 256 + threadIdx.x;
    const float x0 = box[r * 4 + 0], x1 = box[r * 4 + 1];
    const float x2 = box[r * 4 + 2], x3 = box[r * 4 + 3];
    float va = x0 * Wba[c] + x1 * Wba[kD + c] + x2 * Wba[2 * kD + c] + x3 * Wba[3 * kD + c];
    float vb = x0 * Wbb[c] + x1 * Wbb[kD + c] + x2 * Wbb[2 * kD + c] + x3 * Wbb[3 * kD + c];
    ba[(size_t)r * kD + c] = va;
    bb[(size_t)r * kD + c] = vb;
}

// ---------------------------------------------------------------------------
// Staging helpers for k1/k2: Rx32 bf16 tiles via global_load_lds width=16.
// ---------------------------------------------------------------------------
__device__ inline void stage128(const unsigned short* __restrict__ g,
                                int grow0, int k0,
                                unsigned short* lds, int w, int lane)
{
    const int sr = lane >> 2, sc = (lane & 3) * 8;
    #pragma unroll
    for (int t = 0; t < 2; ++t) {
        int r = w * 32 + t * 16;
        const unsigned short* gp = g + (size_t)(grow0 + r + sr) * kD + k0 + sc;
        __builtin_amdgcn_global_load_lds((glb_u32*)gp, (lds_u32*)(lds + r * 32), 16, 0, 0);
    }
}
__device__ inline void stage64(const unsigned short* __restrict__ g,
                               int grow0, int k0,
                               unsigned short* lds, int w, int lane)
{
    const int sr = lane >> 2, sc = (lane & 3) * 8;
    int r = w * 16;
    const unsigned short* gp = g + (size_t)(grow0 + r + sr) * kD + k0 + sc;
    __builtin_amdgcn_global_load_lds((glb_u32*)gp, (lds_u32*)(lds + r * 32), 16, 0, 0);
}

// ---------------------------------------------------------------------------
// K1 (MFMA dual): fused_bf16 = bf16((Qb @ WqT') .* (Ob @ WoT')), 128x64 tile
// ---------------------------------------------------------------------------
__global__ __launch_bounds__(256, 2)
void k1_dual_mfma(const unsigned short* __restrict__ Qb,
                  const unsigned short* __restrict__ WqT,
                  const unsigned short* __restrict__ Ob,
                  const unsigned short* __restrict__ WoT,
                  unsigned short* __restrict__ fusedb)
{
    __shared__ __align__(16) unsigned short As1[128][32];
    __shared__ __align__(16) unsigned short As2[128][32];
    __shared__ __align__(16) unsigned short Bs1[64][32];
    __shared__ __align__(16) unsigned short Bs2[64][32];

    const int tid = threadIdx.x;
    const int lane = tid & 63;
    const int w = tid >> 6;
    const int wm = w >> 1, wn = w & 1;
    const int row0 = blockIdx.y * 128;
    const int col0 = blockIdx.x * 64;

    f32x4 acc1[4][2], acc2[4][2];
    #pragma unroll
    for (int mt = 0; mt < 4; ++mt)
        #pragma unroll
        for (int nt = 0; nt < 2; ++nt) { acc1[mt][nt] = (f32x4)(0.f); acc2[mt][nt] = (f32x4)(0.f); }

    const int fr = lane & 15, ko = (lane >> 4) * 8;

    for (int k0 = 0; k0 < kD; k0 += 32) {
        stage128(Qb,  row0, k0, &As1[0][0], w, lane);
        stage128(Ob,  row0, k0, &As2[0][0], w, lane);
        stage64 (WqT, col0, k0, &Bs1[0][0], w, lane);
        stage64 (WoT, col0, k0, &Bs2[0][0], w, lane);
        __syncthreads();

        bf16x8 a1[4], a2[4];
        #pragma unroll
        for (int mt = 0; mt < 4; ++mt) {
            a1[mt] = *(bf16x8*)&As1[wm * 64 + mt * 16 + fr][ko];
            a2[mt] = *(bf16x8*)&As2[wm * 64 + mt * 16 + fr][ko];
        }
        #pragma unroll
        for (int nt = 0; nt < 2; ++nt) {
            bf16x8 b1 = *(bf16x8*)&Bs1[wn * 32 + nt * 16 + fr][ko];
            bf16x8 b2 = *(bf16x8*)&Bs2[wn * 32 + nt * 16 + fr][ko];
            #pragma unroll
            for (int mt = 0; mt < 4; ++mt) {
                acc1[mt][nt] = __builtin_amdgcn_mfma_f32_16x16x32_bf16(a1[mt], b1, acc1[mt][nt], 0, 0, 0);
                acc2[mt][nt] = __builtin_amdgcn_mfma_f32_16x16x32_bf16(a2[mt], b2, acc2[mt][nt], 0, 0, 0);
            }
        }
        __syncthreads();
    }

    const int fq = lane >> 4;
    #pragma unroll
    for (int mt = 0; mt < 4; ++mt)
        #pragma unroll
        for (int nt = 0; nt < 2; ++nt) {
            int row = row0 + wm * 64 + mt * 16 + fq * 4;
            int col = col0 + wn * 32 + nt * 16 + fr;
            #pragma unroll
            for (int reg = 0; reg < 4; ++reg) {
                float v = acc1[mt][nt][reg] * acc2[mt][nt][reg];
                fusedb[(size_t)(row + reg) * kD + col] = f2bf(v);
            }
        }
}

// ---------------------------------------------------------------------------
// K2 (MFMA dual-B): ra = Fb @ WfaT', rb = Fb @ WfbT', 128x64 tile
// ---------------------------------------------------------------------------
__global__ __launch_bounds__(256, 2)
void k2_dual_mfma(const unsigned short* __restrict__ Fb,
                  const unsigned short* __restrict__ WfaT,
                  const unsigned short* __restrict__ WfbT,
                  float* __restrict__ ra, float* __restrict__ rb)
{
    __shared__ __align__(16) unsigned short As [128][32];
    __shared__ __align__(16) unsigned short Bs1[64][32];
    __shared__ __align__(16) unsigned short Bs2[64][32];

    const int tid = threadIdx.x;
    const int lane = tid & 63;
    const int w = tid >> 6;
    const int wm = w >> 1, wn = w & 1;
    const int row0 = blockIdx.y * 128;
    const int col0 = blockIdx.x * 64;

    f32x4 acc1[4][2], acc2[4][2];
    #pragma unroll
    for (int mt = 0; mt < 4; ++mt)
        #pragma unroll
        for (int nt = 0; nt < 2; ++nt) { acc1[mt][nt] = (f32x4)(0.f); acc2[mt][nt] = (f32x4)(0.f); }

    const int fr = lane & 15, ko = (lane >> 4) * 8;

    for (int k0 = 0; k0 < kD; k0 += 32) {
        stage128(Fb,   row0, k0, &As [0][0], w, lane);
        stage64 (WfaT, col0, k0, &Bs1[0][0], w, lane);
        stage64 (WfbT, col0, k0, &Bs2[0][0], w, lane);
        __syncthreads();

        bf16x8 a[4];
        #pragma unroll
        for (int mt = 0; mt < 4; ++mt)
            a[mt] = *(bf16x8*)&As[wm * 64 + mt * 16 + fr][ko];
        #pragma unroll
        for (int nt = 0; nt < 2; ++nt) {
            bf16x8 b1 = *(bf16x8*)&Bs1[wn * 32 + nt * 16 + fr][ko];
            bf16x8 b2 = *(bf16x8*)&Bs2[wn * 32 + nt * 16 + fr][ko];
            #pragma unroll
            for (int mt = 0; mt < 4; ++mt) {
                acc1[mt][nt] = __builtin_amdgcn_mfma_f32_16x16x32_bf16(a[mt], b1, acc1[mt][nt], 0, 0, 0);
                acc2[mt][nt] = __builtin_amdgcn_mfma_f32_16x16x32_bf16(a[mt], b2, acc2[mt][nt], 0, 0, 0);
            }
        }
        __syncthreads();
    }

    const int fq = lane >> 4;
    #pragma unroll
    for (int mt = 0; mt < 4; ++mt)
        #pragma unroll
        for (int nt = 0; nt < 2; ++nt) {
            int row = row0 + wm * 64 + mt * 16 + fq * 4;
            int col = col0 + wn * 32 + nt * 16 + fr;
            #pragma unroll
            for (int reg = 0; reg < 4; ++reg) {
                size_t o = (size_t)(row + reg) * kD + col;
                ra[o] = acc1[mt][nt][reg];
                rb[o] = acc2[mt][nt][reg];
            }
        }
}

// ---------------------------------------------------------------------------
// K4 v7: 1024-thread block (16 waves = 4 waves/SIMD) to hide the per-step
// dependency chain. v6 showed ~35% LDS-port / 25% VALU / 23% MFMA at
// 2 waves/SIMD -- latency-bound, not throughput-bound. Wave grid 2M x 8N
// (per-wave 64x64 tile, acc = 64 regs/lane) keeps combined VGPR <= 128 so
// a 16-wave block is launchable. One rel-gen slot and <=1 stage slot per
// thread. Pipeline, buffers, hazards, math identical to v6.
// ---------------------------------------------------------------------------
__global__ __launch_bounds__(1024)
void k4_scores_mfma(const float* __restrict__ ra, const float* __restrict__ rb,
                    const float* __restrict__ ba, const float* __restrict__ bb,
                    const unsigned short* __restrict__ W0s,
                    const float* __restrict__ b0, const float* __restrict__ W1,
                    float* __restrict__ scores)
{
    __shared__ __align__(16) unsigned short Bs[2][512 * 32];  // 64 KB
    __shared__ __align__(16) unsigned short RelS[2][128][40]; // 20 KB
    __shared__ __align__(16) float4 Stg4[2][714];             // 22.3 KB : 42 rows x 17 f4
    __shared__ float scoreS[128];

    const int tid  = threadIdx.x;
    const int lane = tid & 63;
    const int w    = tid >> 6;        // 0..15
    const int wm   = w >> 3;          // 0..1 : M-half (64 rows)
    const int wn   = w & 7;           // 0..7 : N-eighth (64 cols)

    // XCD-chunked swizzle: 704 = 8 XCDs x 88; same-b tiles stay on one XCD
    const int work = (blockIdx.x & 7) * 88 + (blockIdx.x >> 3);
    const int b    = work / 11;
    const int tile = work - b * 11;   // 0..10 (tile 10: 16 valid rows)
    const int p0   = tile * 128;      // first pair index within b
    const int i0   = p0 / kN;

    const float* raB = ra + (size_t)b * kN * kD;
    const float* rbB = rb + (size_t)b * kN * kD;
    const float* baB = ba + (size_t)b * kN * kD;
    const float* bbB = bb + (size_t)b * kN * kD;

    // ---- stage slots: 672 = 42 rows x 16 f4 (rows 0..5 = i-rows ra/ba,
    //      rows 6..41 = j-rows rb/bb; per row: f4 0..7 = arr0, 8..15 = arr1)
    const bool hasStage = (tid < 672);
    const float* sptr;
    int sdst;
    {
        int s = hasStage ? tid : 671;
        int row = s >> 4, t4 = s & 15;
        int arr = t4 >> 3, q = t4 & 7;
        int grow; const float* base;
        if (row < 6) {
            int il = (row < 5) ? row : 4;
            grow = i0 + il; if (grow > kN - 1) grow = kN - 1;
            base = arr ? baB : raB;
        } else {
            grow = row - 6;
            base = arr ? bbB : rbB;
        }
        sptr = base + (size_t)grow * kD + q * 4;
        sdst = row * 17 + t4;
    }

    // ---- Rel-gen slot: 1024 = 128 rows x 8 col-groups; one per thread
    int rowA, cgA, ilA, jA;
    {
        rowA = tid >> 3; cgA = tid & 7;
        int p = p0 + rowA; if (p >= kPairs) p = kPairs - 1;
        int i = p / kN;
        jA  = p - i * kN;
        ilA = i - i0;
    }

    const int fr = lane & 15, fq = lane >> 4;
    const int bco = ((fr & 7) << 3) + ((fr >> 3) << 8) + (fq << 6);

    f32x4 acc[4][4];
    #pragma unroll
    for (int mt = 0; mt < 4; ++mt)
        #pragma unroll
        for (int nt = 0; nt < 4; ++nt)
            acc[mt][nt] = (f32x4)(0.f);

    if (tid < 128) scoreS[tid] = 0.f;

    float4 sreg0;

    #define ISSUE_B(k0_, buf_)                                                   \
        _Pragma("unroll")                                                        \
        for (int t = 0; t < 2; ++t) {                                            \
            int chunk = w * 2 + t;                                               \
            const unsigned short* gp = W0s + (size_t)((k0_) >> 5) * 16384        \
                                       + chunk * 512 + lane * 8;                 \
            __builtin_amdgcn_global_load_lds((glb_u32*)gp,                       \
                (lds_u32*)&Bs[buf_][chunk * 512], 16, 0, 0);                     \
        }

    #define STAGE_LOAD(k0_) {                                                    \
            if (hasStage) sreg0 = *(const float4*)(sptr + (k0_));                \
        }

    #define STAGE_WRITE(buf_) {                                                  \
            if (hasStage) Stg4[buf_][sdst] = sreg0;                              \
        }

    #define REL_GEN(buf_) {                                                      \
            float4 va = Stg4[buf_][ilA * 17 + cgA];                              \
            float4 vb = Stg4[buf_][ilA * 17 + 8 + cgA];                          \
            float4 vr = Stg4[buf_][(6 + jA) * 17 + cgA];                         \
            float4 vq = Stg4[buf_][(6 + jA) * 17 + 8 + cgA];                     \
            ushort4 o;                                                           \
            o.x = f2bf(va.x * vr.x + vb.x * vq.x);                               \
            o.y = f2bf(va.y * vr.y + vb.y * vq.y);                               \
            o.z = f2bf(va.z * vr.z + vb.z * vq.z);                               \
            o.w = f2bf(va.w * vr.w + vb.w * vq.w);                               \
            *(ushort4*)&RelS[buf_][rowA][cgA * 4] = o;                           \
        }

    // ---- prologue: RelS[0], Stg[1], Bs[0]
    STAGE_LOAD(0)
    STAGE_WRITE(0)
    STAGE_LOAD(32)
    __syncthreads();          // Stg[0] visible
    REL_GEN(0)
    STAGE_WRITE(1)
    ISSUE_B(0, 0)

    for (int k = 0; k < 64; ++k) {
        const int cur = k & 1, nxt = cur ^ 1;
        __syncthreads();      // Bs[cur] drained; RelS[cur], Stg[nxt] visible
        if (k < 62) STAGE_LOAD((k + 2) * 32)
        if (k < 63) ISSUE_B((k + 1) * 32, nxt)
        bf16x8 af[4];
        #pragma unroll
        for (int mt = 0; mt < 4; ++mt)
            af[mt] = *(bf16x8*)&RelS[cur][wm * 64 + mt * 16 + fr][fq * 8];
        #pragma unroll
        for (int nt = 0; nt < 4; ++nt) {
            bf16x8 bfv = *(bf16x8*)&Bs[cur][wn * 2048 + nt * 512 + bco];
            #pragma unroll
            for (int mt = 0; mt < 4; ++mt)
                acc[mt][nt] = __builtin_amdgcn_mfma_f32_16x16x32_bf16(af[mt], bfv, acc[mt][nt], 0, 0, 0);
        }
        if (k < 62) STAGE_WRITE(cur)   // step k+2's data into Stg[k&1]
        if (k < 63) REL_GEN(nxt)       // RelS[(k+1)&1] from Stg[(k+1)&1]
    }

    // epilogue: score_row = sum_cols W1*tanh(H + b0); b1 softmax-invariant
    float b0v[4], w1v[4];
    #pragma unroll
    for (int nt = 0; nt < 4; ++nt) {
        int col = wn * 64 + nt * 16 + fr;
        b0v[nt] = b0[col];
        w1v[nt] = W1[col];
    }
    #pragma unroll
    for (int mt = 0; mt < 4; ++mt) {
        #pragma unroll
        for (int reg = 0; reg < 4; ++reg) {
            float p = 0.f;
            #pragma unroll
            for (int nt = 0; nt < 4; ++nt)
                p += w1v[nt] * tanhf(acc[mt][nt][reg] + b0v[nt]);
            p += __shfl_xor(p, 1, 64);
            p += __shfl_xor(p, 2, 64);
            p += __shfl_xor(p, 4, 64);
            p += __shfl_xor(p, 8, 64);
            if (fr == 0)
                atomicAdd(&scoreS[wm * 64 + mt * 16 + fq * 4 + reg], p);
        }
    }
    __syncthreads();
    if (tid < 128 && p0 + tid < kPairs)
        scores[(size_t)b * kPairs + p0 + tid] = scoreS[tid];
}

// ---------------------------------------------------------------------------
// K5: softmax over j
// ---------------------------------------------------------------------------
__global__ __launch_bounds__(64)
void k5_softmax(const float* __restrict__ scores, float* __restrict__ att)
{
    const int bi = blockIdx.x;
    const int tid = threadIdx.x;
    float s = (tid < kN) ? scores[(size_t)bi * kN + tid] : -1e30f;
    float m = s;
    #pragma unroll
    for (int off = 32; off >= 1; off >>= 1)
        m = fmaxf(m, __shfl_xor(m, off, 64));
    float e = (tid < kN) ? expf(s - m) : 0.f;
    float sum = e;
    #pragma unroll
    for (int off = 32; off >= 1; off >>= 1)
        sum += __shfl_xor(sum, off, 64);
    if (tid < kN) att[(size_t)bi * kN + tid] = e / sum;
}

// ---------------------------------------------------------------------------
// K6: out[b,i,:] = obj + fused + ra_i.(att_i @ RB_b) + ba_i.(att_i @ BB_b)
// ---------------------------------------------------------------------------
__global__ __launch_bounds__(256)
void k6_output(const float* __restrict__ obj, const unsigned short* __restrict__ fusedb,
               const float* __restrict__ ra, const float* __restrict__ ba,
               const float* __restrict__ rb, const float* __restrict__ bb,
               const float* __restrict__ att, float* __restrict__ out)
{
    __shared__ float attS[kN];
    const int bi = blockIdx.x;
    const int b = bi / kN;
    const int tid = threadIdx.x;
    if (tid < kN) attS[tid] = att[(size_t)bi * kN + tid];
    __syncthreads();
    for (int d = tid; d < kD; d += 256) {
        float s1 = 0.f, s2 = 0.f;
        #pragma unroll 4
        for (int j = 0; j < kN; ++j) {
            float a = attS[j];
            size_t rrow = (size_t)(b * kN + j) * kD + d;
            s1 = fmaf(a, rb[rrow], s1);
            s2 = fmaf(a, bb[rrow], s2);
        }
        size_t o = (size_t)bi * kD + d;
        float fv = __uint_as_float((u32)fusedb[o] << 16);
        out[o] = obj[o] + fv + ra[o] * s1 + ba[o] * s2;
    }
}

// ---------------------------------------------------------------------------
extern "C" void kernel_launch(void* const* d_in, const int* in_sizes, int n_in,
                              void* d_out, int out_size, void* d_ws, size_t ws_size,
                              hipStream_t stream)
{
    const float* q   = (const float*)d_in[0];
    const float* obj = (const float*)d_in[1];
    const float* box = (const float*)d_in[2];
    const float* Wq  = (const float*)d_in[3];
    const float* Wo  = (const float*)d_in[4];
    const float* Wfa = (const float*)d_in[5];
    const float* Wfb = (const float*)d_in[6];
    const float* Wba = (const float*)d_in[7];
    const float* Wbb = (const float*)d_in[8];
    const float* W0  = (const float*)d_in[9];
    const float* b0v = (const float*)d_in[10];
    const float* W1  = (const float*)d_in[11];
    // d_in[12] = b1 (softmax-invariant), d_in[13..14] scalars: unused
    float* out = (float*)d_out;

    const size_t nBD = (size_t)kBN * kD;
    float* ws = (float*)d_ws;
    size_t off = 0;
    float* ra     = ws + off; off += nBD;
    float* rb     = ws + off; off += nBD;
    float* ba     = ws + off; off += nBD;
    float* bb     = ws + off; off += nBD;
    float* scores = ws + off; off += (size_t)kBN * kN;
    float* att    = ws + off; off += (size_t)kBN * kN;

    unsigned short* us = (unsigned short*)(ws + off);
    size_t uoff = 0;
    unsigned short* W0T     = us + uoff; uoff += (size_t)kDatt * kD;
    unsigned short* W0s     = us + uoff; uoff += (size_t)kDatt * kD;
    unsigned short* q_bf    = us + uoff; uoff += nBD;
    unsigned short* obj_bf  = us + uoff; uoff += nBD;
    unsigned short* fusedbf = us + uoff; uoff += nBD;
    unsigned short* WqT     = us + uoff; uoff += (size_t)kD * kD;
    unsigned short* WoT     = us + uoff; uoff += (size_t)kD * kD;
    // WfaT/WfbT alias q_bf/obj_bf (dead after k1; stream order guarantees safety)
    unsigned short* WfaT = q_bf;
    unsigned short* WfbT = obj_bf;

    const int n4 = (int)(nBD / 4);
    kcvt<<<dim3((n4 + 255) / 256), 256, 0, stream>>>(q,   q_bf,   n4);
    kcvt<<<dim3((n4 + 255) / 256), 256, 0, stream>>>(obj, obj_bf, n4);
    ktrp<<<dim3(32, 32), 256, 0, stream>>>(Wq, WqT, kD);
    ktrp<<<dim3(32, 32), 256, 0, stream>>>(Wo, WoT, kD);
    ktrp<<<dim3(32, 8),  256, 0, stream>>>(W0, W0T, kDatt);
    krepack_w0<<<dim3(kD / 32, kDatt / 16), 64, 0, stream>>>(W0T, W0s);
    k3_box_proj<<<dim3(kD / 256, kBN), 256, 0, stream>>>(box, Wba, Wbb, ba, bb);

    k1_dual_mfma<<<dim3(kD / 64, kBN / 128), 256, 0, stream>>>(q_bf, WqT, obj_bf, WoT, fusedbf);

    ktrp<<<dim3(32, 32), 256, 0, stream>>>(Wfa, WfaT, kD);
    ktrp<<<dim3(32, 32), 256, 0, stream>>>(Wfb, WfbT, kD);

    k2_dual_mfma<<<dim3(kD / 64, kBN / 128), 256, 0, stream>>>(fusedbf, WfaT, WfbT, ra, rb);

    k4_scores_mfma<<<dim3(kB * 11), 1024, 0, stream>>>(ra, rb, ba, bb, W0s, b0v, W1, scores);
    k5_softmax<<<kBN, 64, 0, stream>>>(scores, att);
    k6_output<<<kBN, 256, 0, stream>>>(obj, fusedbf, ra, ba, rb, bb, att, out);
}